// Round 5
// baseline (1601.668 us; speedup 1.0000x reference)
//
#include <hip/hip_runtime.h>
#include <cstdint>

// N=50000 nodes, E=1.6M edges, IN=128, H=64, OUT=32, R=8
#define HDIM 64
#define ODIM 32
#define NEG_SLOPE 0.2f
#define SCHUNK 2048
#define EPB 8192  // edges per block in bucket_pass1

typedef __attribute__((ext_vector_type(8))) short v8s;   // 8 bf16 (4 VGPRs)
typedef __attribute__((ext_vector_type(4))) float v4f;   // MFMA accumulator

__device__ __forceinline__ unsigned f2bf_rne(float f) {
  unsigned u = __float_as_uint(f);
  return (u + 0x7FFFu + ((u >> 16) & 1u)) >> 16;  // round-to-nearest-even
}

// monotonic float<->uint order-preserving encode (for atomicMax on floats)
__device__ __forceinline__ unsigned fenc(float f) {
  unsigned u = __float_as_uint(f);
  return (u & 0x80000000u) ? ~u : (u | 0x80000000u);
}
__device__ __forceinline__ float fdec(unsigned e) {
  unsigned u = (e & 0x80000000u) ? (e ^ 0x80000000u) : ~e;
  return __uint_as_float(u);
}

// ---------------------------------------------------------------------------
// Prep: fp32 -> bf16 convert (x); weight transposes:
//   W1t [r][o][kk128] (layer-1 MFMA B), Wct [s][o][512] (out2 MFMA B).
// ---------------------------------------------------------------------------
__global__ __launch_bounds__(256) void cvt_bf16_kernel(
    const float* __restrict__ in, unsigned short* __restrict__ out, int n) {
  int i = (blockIdx.x * 256 + threadIdx.x) * 4;
  if (i + 3 < n) {
    float4 v = *(const float4*)&in[i];
    ushort4 o;
    o.x = (unsigned short)f2bf_rne(v.x);
    o.y = (unsigned short)f2bf_rne(v.y);
    o.z = (unsigned short)f2bf_rne(v.z);
    o.w = (unsigned short)f2bf_rne(v.w);
    *(ushort4*)&out[i] = o;
  }
}

__global__ __launch_bounds__(256) void transpose_w_kernel(
    const float* __restrict__ W1, const float* __restrict__ Wmu,
    const float* __restrict__ Wlv, unsigned short* __restrict__ W1t,
    unsigned short* __restrict__ Wct) {
  const int b = blockIdx.x;  // 0..23
  if (b < 8) {
    const int r = b;
    for (int idx = threadIdx.x; idx < 128 * 64; idx += 256) {
      const int kk = idx >> 6, o = idx & 63;
      W1t[((size_t)r * 64 + o) * 128 + kk] =
          (unsigned short)f2bf_rne(W1[((size_t)r * 128 + kk) * 64 + o]);
    }
  } else {
    const int s = (b - 8) >> 3, r = (b - 8) & 7;
    const float* src = s ? Wlv : Wmu;
    for (int idx = threadIdx.x; idx < 64 * 64; idx += 256) {
      const int kk = idx >> 6, o = idx & 63;
      Wct[((size_t)s * 64 + o) * 512 + r * 64 + kk] =
          (unsigned short)f2bf_rne(src[((size_t)r * 64 + kk) * 64 + o]);
    }
  }
}

// Logit direction table T[32][64] fp32:
//   T[s*8+r][c]    = sum_o W_{s,r}[c][o] * q_s[o]
//   T[16+s*8+r][c] = sum_o W_{s,r}[c][o] * k_s[o]
__global__ __launch_bounds__(256) void prep_T_kernel(
    const float* __restrict__ Wmu, const float* __restrict__ qmu,
    const float* __restrict__ kmu, const float* __restrict__ Wlv,
    const float* __restrict__ qlv, const float* __restrict__ klv,
    float* __restrict__ T) {
  for (int idx = threadIdx.x; idx < 2048; idx += 256) {
    const int j = idx >> 6, c = idx & 63;
    const int isk = j >> 4, sr = j & 15, s = sr >> 3, r = sr & 7;
    const float* W = s ? Wlv : Wmu;
    const float* vec = s ? (isk ? klv : qlv) : (isk ? kmu : qmu);
    float acc = 0.f;
    for (int o = 0; o < 64; o++)
      acc += W[((size_t)r * 64 + c) * 64 + o] * vec[o];
    T[idx] = acc;
  }
}

// ---------------------------------------------------------------------------
// CSR build: degree count + 3-phase scan (R1-exact)
// ---------------------------------------------------------------------------
__global__ __launch_bounds__(256) void count_deg_kernel(
    const int* __restrict__ dst, int* __restrict__ deg, int E) {
  int e = blockIdx.x * 256 + threadIdx.x;
  if (e < E) atomicAdd(&deg[dst[e]], 1);
}

__global__ __launch_bounds__(256) void scan_p1(const int* __restrict__ deg,
                                               int* __restrict__ bsum, int n) {
  int base = blockIdx.x * SCHUNK + threadIdx.x * 8;
  int s = 0;
#pragma unroll
  for (int j = 0; j < 8; j++) {
    int i = base + j;
    if (i < n) s += deg[i];
  }
#pragma unroll
  for (int d = 1; d < 64; d <<= 1) s += __shfl_xor(s, d, 64);
  __shared__ int ws[4];
  if ((threadIdx.x & 63) == 0) ws[threadIdx.x >> 6] = s;
  __syncthreads();
  if (threadIdx.x == 0) bsum[blockIdx.x] = ws[0] + ws[1] + ws[2] + ws[3];
}

__global__ void scan_p2(int* bsum, int nb) {
  int i = threadIdx.x;
  int v = (i < nb) ? bsum[i] : 0;
  int orig = v;
#pragma unroll
  for (int d = 1; d < 64; d <<= 1) {
    int up = __shfl_up(v, d, 64);
    if (i >= d) v += up;
  }
  if (i < nb) bsum[i] = v - orig;
}

__global__ __launch_bounds__(256) void scan_p3(const int* __restrict__ deg,
                                               const int* __restrict__ bsum,
                                               int* __restrict__ row_ptr,
                                               int n) {
  int base = blockIdx.x * SCHUNK + threadIdx.x * 8;
  int vals[8];
  int s = 0;
#pragma unroll
  for (int j = 0; j < 8; j++) {
    int i = base + j;
    vals[j] = (i < n) ? deg[i] : 0;
    s += vals[j];
  }
  int lane = threadIdx.x & 63, w = threadIdx.x >> 6;
  int v = s;
#pragma unroll
  for (int d = 1; d < 64; d <<= 1) {
    int up = __shfl_up(v, d, 64);
    if (lane >= d) v += up;
  }
  __shared__ int wsum[4];
  if (lane == 63) wsum[w] = v;
  __syncthreads();
  int woff = 0;
#pragma unroll
  for (int i = 0; i < 4; i++) woff += (i < w) ? wsum[i] : 0;
  int off = bsum[blockIdx.x] + woff + v - s;
#pragma unroll
  for (int j = 0; j < 8; j++) {
    int i = base + j;
    off += vals[j];
    if (i < n) row_ptr[i + 1] = off;
  }
  if (blockIdx.x == 0 && threadIdx.x == 0) row_ptr[0] = 0;
}

// ---------------------------------------------------------------------------
// Bucketed edge placement (2-pass; R1-exact).
// ---------------------------------------------------------------------------
__global__ __launch_bounds__(256) void bucket_cursor_init(
    const int* __restrict__ row_ptr, int* __restrict__ cursor, int N, int nb) {
  int i = threadIdx.x;
  if (i < nb) cursor[i] = row_ptr[min(i * 256, N)];
}

__global__ __launch_bounds__(256) void bucket_pass1(
    const int* __restrict__ src, const int* __restrict__ dst,
    const int* __restrict__ etype, int* __restrict__ cursor,
    unsigned* __restrict__ tmp, int E) {
  __shared__ int hist[256];
  __shared__ int binstart[256];
  __shared__ int gbase[256];
  __shared__ int fill[256];
  __shared__ int wsum[4];
  __shared__ unsigned stage[EPB];
  __shared__ unsigned char binof[EPB];
  const int tid = threadIdx.x;
  const int e0 = blockIdx.x * EPB;
  const int cnt = min(EPB, E - e0);

  hist[tid] = 0;
  fill[tid] = 0;
  __syncthreads();
  for (int j = tid; j < cnt; j += 256) atomicAdd(&hist[dst[e0 + j] >> 8], 1);
  __syncthreads();

  const int hv = hist[tid];
  {
    const int lane = tid & 63, w = tid >> 6;
    int iv = hv;
#pragma unroll
    for (int d = 1; d < 64; d <<= 1) {
      int up = __shfl_up(iv, d, 64);
      if (lane >= d) iv += up;
    }
    if (lane == 63) wsum[w] = iv;
    __syncthreads();
    int woff = 0;
#pragma unroll
    for (int i = 0; i < 4; i++) woff += (i < w) ? wsum[i] : 0;
    binstart[tid] = woff + iv - hv;  // exclusive prefix
    if (hv > 0) gbase[tid] = atomicAdd(&cursor[tid], hv);
  }
  __syncthreads();

  for (int j = tid; j < cnt; j += 256) {
    const int d = dst[e0 + j];
    const int b = d >> 8;
    const unsigned rec = ((unsigned)(d & 255) << 19) |
                         ((unsigned)etype[e0 + j] << 16) |
                         (unsigned)src[e0 + j];
    const int slot = binstart[b] + atomicAdd(&fill[b], 1);
    stage[slot] = rec;
    binof[slot] = (unsigned char)b;
  }
  __syncthreads();

  for (int s = tid; s < cnt; s += 256) {
    const int b = binof[s];
    tmp[gbase[b] + (s - binstart[b])] = stage[s];
  }
}

__global__ __launch_bounds__(256) void bucket_pass2(
    const int* __restrict__ row_ptr, const unsigned* __restrict__ tmp,
    int* __restrict__ edges, int N) {
  __shared__ int rp[257];
  __shared__ int fill[256];
  const int tid = threadIdx.x;
  const int rowbase = blockIdx.x * 256;
  const int rowcnt = min(256, N - rowbase);
  for (int i = tid; i <= rowcnt; i += 256) rp[i] = row_ptr[rowbase + i];
  fill[tid] = 0;
  __syncthreads();
  const int beg = rp[0];
  const int endv = rp[rowcnt];
  for (int i = beg + tid; i < endv; i += 256) {
    const unsigned rec = tmp[i];
    const int dlow = rec >> 19;
    const int pos = rp[dlow] + atomicAdd(&fill[dlow], 1);
    edges[pos] = (int)(rec & 0x7FFFFu);  // src | etype<<16
  }
}

// ---------------------------------------------------------------------------
// Layer-1 transform via MFMA bf16 (R1 grid (R, nb64) form) + folded rowmax:
// per-block atomicMax(maxk_enc[r]) replaces the separate rowmax pass.
// ---------------------------------------------------------------------------
__global__ __launch_bounds__(256) void transform1_mfma(
    const unsigned short* __restrict__ xb,
    const unsigned short* __restrict__ W1t, const float* __restrict__ q,
    const float* __restrict__ k, unsigned short* __restrict__ tb,
    float* __restrict__ aq, float* __restrict__ ak,
    unsigned* __restrict__ maxk_enc, int N) {
  __shared__ unsigned short st[4][16][72];
  __shared__ float wsm[4];
  const int r = blockIdx.x;
  const int tid = threadIdx.x;
  const int w = tid >> 6;
  const int lane = tid & 63;
  const int quad = lane >> 4;
  const int mrow = lane & 15;
  const int n0w = blockIdx.y * 64 + w * 16;

  const int gA = min(n0w + mrow, N - 1);
  const unsigned short* arow = xb + (size_t)gA * 128 + quad * 8;
  const unsigned short* wrow = W1t + ((size_t)r * 64 + mrow) * 128 + quad * 8;

  v4f acc[4];
#pragma unroll
  for (int tt = 0; tt < 4; tt++) acc[tt] = (v4f){0.f, 0.f, 0.f, 0.f};

#pragma unroll
  for (int k0 = 0; k0 < 128; k0 += 32) {
    v8s a = *(const v8s*)(arow + k0);
#pragma unroll
    for (int tt = 0; tt < 4; tt++) {
      v8s b = *(const v8s*)(wrow + (size_t)tt * 16 * 128 + k0);
      acc[tt] = __builtin_amdgcn_mfma_f32_16x16x32_bf16(a, b, acc[tt], 0, 0, 0);
    }
  }

  float qv[4], kv[4];
#pragma unroll
  for (int tt = 0; tt < 4; tt++) {
    qv[tt] = q[tt * 16 + mrow];
    kv[tt] = k[tt * 16 + mrow];
  }

  float kmax = -1e30f;
#pragma unroll
  for (int i = 0; i < 4; i++) {
    float vq = 0.f, vk = 0.f;
#pragma unroll
    for (int tt = 0; tt < 4; tt++) {
      vq = fmaf(acc[tt][i], qv[tt], vq);
      vk = fmaf(acc[tt][i], kv[tt], vk);
      st[w][quad * 4 + i][tt * 16 + mrow] =
          (unsigned short)f2bf_rne(acc[tt][i]);
    }
#pragma unroll
    for (int d = 1; d < 16; d <<= 1) {
      vq += __shfl_xor(vq, d, 64);
      vk += __shfl_xor(vk, d, 64);
    }
    kmax = fmaxf(kmax, vk);
    const int gn = n0w + quad * 4 + i;
    if (mrow == 0 && gn < N) {
      aq[(size_t)r * N + gn] = vq;
      ak[(size_t)r * N + gn] = vk;
    }
  }
#pragma unroll
  for (int d = 1; d < 64; d <<= 1) kmax = fmaxf(kmax, __shfl_xor(kmax, d, 64));
  if (lane == 0) wsm[w] = kmax;
  __syncthreads();
  if (tid == 0) {
    atomicMax(&maxk_enc[r],
              fenc(fmaxf(fmaxf(wsm[0], wsm[1]), fmaxf(wsm[2], wsm[3]))));
  }

  const int row = lane >> 2, cg = lane & 3;
  const int gns = n0w + row;
  if (gns < N) {
    const uint4 v0 = *(const uint4*)&st[w][row][cg * 16];
    const uint4 v1 = *(const uint4*)&st[w][row][cg * 16 + 8];
    uint4* dst = (uint4*)&tb[((size_t)r * N + gns) * 64 + cg * 16];
    dst[0] = v0;
    dst[1] = v1;
  }
}

// ---------------------------------------------------------------------------
// Layer-1 aggregate: R1-exact best-measured form (u-loop group gather).
// ---------------------------------------------------------------------------
__global__ __launch_bounds__(256) void aggregate_kernel(
    const int* __restrict__ row_ptr, const int* __restrict__ edges,
    const unsigned short* __restrict__ tb, const float* __restrict__ aq,
    const float* __restrict__ ak, const unsigned* __restrict__ maxk_enc,
    const float* __restrict__ bias, unsigned short* __restrict__ hb, int N) {
  const int tid = threadIdx.x;
  const int w = tid >> 6, o = tid & 63;
  int wid = blockIdx.x * 4 + w;
  const bool valid = wid < N;
  if (!valid) wid = N - 1;
  const int beg = row_ptr[wid];
  const int end = valid ? row_ptr[wid + 1] : beg;
  const int deg = end - beg;

  const float aqw = aq[(size_t)(o & 7) * N + wid];

  float v = aqw + fdec(maxk_enc[o & 7]);
  v = (v >= 0.f) ? v : NEG_SLOPE * v;
#pragma unroll
  for (int d = 1; d < 8; d <<= 1) v = fmaxf(v, __shfl_xor(v, d, 64));
  const float m = __shfl(v, 0, 64);

  const int g = o >> 3;  // edge-group 0..7 (8 edges per gather iter)
  const int cl = o & 7;  // channel lane: owns channels 8*cl .. 8*cl+7
  float s = 0.f;
  float acc[8];
#pragma unroll
  for (int c = 0; c < 8; c++) acc[c] = 0.f;

  for (int base = 0; base < deg; base += 64) {
    const int j = base + o;
    const int gcount = min(64, deg - base);
    const int packed = edges[beg + min(j, deg - 1)];
    const int src = packed & 0xFFFF;
    const int rr = packed >> 16;
    const int idx = rr * N + src;
    float x = __shfl(aqw, rr, 64) + ak[idx];
    x = (x >= 0.f) ? x : NEG_SLOPE * x;
    const float p = (j < deg) ? __expf(x - m) : 0.f;
    s += p;
    const int g8 = (gcount + 7) & ~7;
    for (int u = 0; u < g8; u += 8) {
      const int e = u + g;
      const float pe = __shfl(p, e, 64);   // 0 for padded slots
      const int ie = __shfl(idx, e, 64);   // clamped-valid index
      const uint4 tv = *(const uint4*)(tb + (size_t)ie * 64 + cl * 8);
      const unsigned uu0 = tv.x, uu1 = tv.y, uu2 = tv.z, uu3 = tv.w;
      acc[0] = fmaf(pe, __uint_as_float(uu0 << 16), acc[0]);
      acc[1] = fmaf(pe, __uint_as_float(uu0 & 0xFFFF0000u), acc[1]);
      acc[2] = fmaf(pe, __uint_as_float(uu1 << 16), acc[2]);
      acc[3] = fmaf(pe, __uint_as_float(uu1 & 0xFFFF0000u), acc[3]);
      acc[4] = fmaf(pe, __uint_as_float(uu2 << 16), acc[4]);
      acc[5] = fmaf(pe, __uint_as_float(uu2 & 0xFFFF0000u), acc[5]);
      acc[6] = fmaf(pe, __uint_as_float(uu3 << 16), acc[6]);
      acc[7] = fmaf(pe, __uint_as_float(uu3 & 0xFFFF0000u), acc[7]);
    }
  }
#pragma unroll
  for (int d = 1; d < 64; d <<= 1) s += __shfl_xor(s, d, 64);
#pragma unroll
  for (int d = 8; d < 64; d <<= 1) {
#pragma unroll
    for (int c = 0; c < 8; c++) acc[c] += __shfl_xor(acc[c], d, 64);
  }

  if (valid && g == 0) {
    const float inv = 1.f / (s + 1e-16f);
    unsigned rv[8];
#pragma unroll
    for (int c = 0; c < 8; c++) {
      const float res = acc[c] * inv + bias[cl * 8 + c];
      rv[c] = f2bf_rne(fmaxf(res, 0.f));
    }
    uint4 pkd;
    pkd.x = rv[0] | (rv[1] << 16);
    pkd.y = rv[2] | (rv[3] << 16);
    pkd.z = rv[4] | (rv[5] << 16);
    pkd.w = rv[6] | (rv[7] << 16);
    *(uint4*)(hb + (size_t)wid * 64 + cl * 8) = pkd;
  }
}

// ---------------------------------------------------------------------------
// Layer-2 logits: aq2[j,n] = h_n.T[j], ak2[j,n] = h_n.T[16+j]; folded rowmax.
// ---------------------------------------------------------------------------
__global__ __launch_bounds__(256) void logit2_kernel(
    const unsigned short* __restrict__ hb, const float* __restrict__ T,
    float* __restrict__ aq2, float* __restrict__ ak2,
    unsigned* __restrict__ maxk2_enc, int N) {
  __shared__ float Ts[2048];
  __shared__ float wred[4][16];
  for (int i = threadIdx.x; i < 2048; i += 256) Ts[i] = T[i];
  __syncthreads();
  const int n0 = blockIdx.x * 256 + threadIdx.x;
  const bool valid = n0 < N;
  const int n = valid ? n0 : N - 1;
  float h[64];
  const unsigned short* hr = hb + (size_t)n * 64;
#pragma unroll
  for (int d = 0; d < 8; d++) {
    const uint4 u = *(const uint4*)(hr + d * 8);
    h[d * 8 + 0] = __uint_as_float(u.x << 16);
    h[d * 8 + 1] = __uint_as_float(u.x & 0xFFFF0000u);
    h[d * 8 + 2] = __uint_as_float(u.y << 16);
    h[d * 8 + 3] = __uint_as_float(u.y & 0xFFFF0000u);
    h[d * 8 + 4] = __uint_as_float(u.z << 16);
    h[d * 8 + 5] = __uint_as_float(u.z & 0xFFFF0000u);
    h[d * 8 + 6] = __uint_as_float(u.w << 16);
    h[d * 8 + 7] = __uint_as_float(u.w & 0xFFFF0000u);
  }
  float kmx[16];
#pragma unroll
  for (int j = 0; j < 16; j++) {
    float dq = 0.f, dk = 0.f;
#pragma unroll
    for (int c = 0; c < 64; c++) {
      dq = fmaf(h[c], Ts[j * 64 + c], dq);
      dk = fmaf(h[c], Ts[(16 + j) * 64 + c], dk);
    }
    if (valid) {
      aq2[(size_t)j * N + n] = dq;
      ak2[(size_t)j * N + n] = dk;
    }
    kmx[j] = dk;  // invalid lanes carry node N-1 dup: max unaffected
  }
  const int lane = threadIdx.x & 63, w = threadIdx.x >> 6;
#pragma unroll
  for (int j = 0; j < 16; j++) {
#pragma unroll
    for (int d = 1; d < 64; d <<= 1)
      kmx[j] = fmaxf(kmx[j], __shfl_xor(kmx[j], d, 64));
    if (lane == 0) wred[w][j] = kmx[j];
  }
  __syncthreads();
  if (threadIdx.x < 16) {
    const float bm = fmaxf(fmaxf(wred[0][threadIdx.x], wred[1][threadIdx.x]),
                           fmaxf(wred[2][threadIdx.x], wred[3][threadIdx.x]));
    atomicMax(&maxk2_enc[threadIdx.x], fenc(bm));
  }
}

// ---------------------------------------------------------------------------
// Layer-2 aggregate over h (relation-factored, LDS ds_add_f32 scatter):
// R1 window structure (full lane utilization), per-wave y[8][64] fp32 x2
// streams in LDS with (ch + 8r)&63 skew (disjoint bank sets per group).
// Gathers 128B h rows from the 6.4MB L2/L3-resident hb. Writes unnormalized
// y[s][node][r*64+ch] bf16 + softmax sums sbuf[node][2].
// ---------------------------------------------------------------------------
__global__ __launch_bounds__(256) void aggregate2h_kernel(
    const int* __restrict__ row_ptr, const int* __restrict__ edges,
    const unsigned short* __restrict__ hb, const float* __restrict__ aq2,
    const float* __restrict__ ak2, const unsigned* __restrict__ maxk2_enc,
    unsigned* __restrict__ y, float* __restrict__ sbuf, int N) {
  __shared__ float y0s[4][512];
  __shared__ float y1s[4][512];
  const int tid = threadIdx.x;
  const int w = tid >> 6, o = tid & 63;
  // wave-private zero-init: each wave owns y*[w]; LDS ops are in-order
  // per wave, so no barrier is needed anywhere in this kernel.
  for (int i = o; i < 512; i += 64) {
    y0s[w][i] = 0.f;
    y1s[w][i] = 0.f;
  }

  int wid = blockIdx.x * 4 + w;
  const bool valid = wid < N;
  if (!valid) wid = N - 1;
  const int beg = row_ptr[wid];
  const int end = valid ? row_ptr[wid + 1] : beg;
  const int deg = end - beg;

  const float aqw = aq2[(size_t)(o & 15) * N + wid];
  float v = aqw + fdec(maxk2_enc[o & 15]);
  v = (v >= 0.f) ? v : NEG_SLOPE * v;
#pragma unroll
  for (int d = 1; d < 8; d <<= 1) v = fmaxf(v, __shfl_xor(v, d, 64));
  const float m0 = __shfl(v, 0, 64);
  const float m1 = __shfl(v, 8, 64);

  const int g = o >> 4;   // edge-group 0..3 (4 edges per gather iter)
  const int cl = o & 15;  // channel lane: owns ch 4*cl .. 4*cl+3
  float s0 = 0.f, s1 = 0.f;

  for (int base = 0; base < deg; base += 64) {
    const int j = base + o;
    const int gcount = min(64, deg - base);
    const int packed = edges[beg + min(j, deg - 1)];
    const int src = packed & 0xFFFF;
    const int rr = packed >> 16;
    const int idx = rr * N + src;
    float x0 = __shfl(aqw, rr, 64) + ak2[idx];
    float x1 = __shfl(aqw, 8 + rr, 64) + ak2[idx + 8 * N];
    x0 = (x0 >= 0.f) ? x0 : NEG_SLOPE * x0;
    x1 = (x1 >= 0.f) ? x1 : NEG_SLOPE * x1;
    const float p0 = (j < deg) ? __expf(x0 - m0) : 0.f;
    const float p1 = (j < deg) ? __expf(x1 - m1) : 0.f;
    s0 += p0;
    s1 += p1;
    const int g4 = (gcount + 3) & ~3;
    for (int u = 0; u < g4; u += 4) {
      const int e = u + g;
      const float pe0 = __shfl(p0, e, 64);    // 0 for padded slots
      const float pe1 = __shfl(p1, e, 64);
      const int pk = __shfl(packed, e, 64);   // clamped-valid record
      const int se_ = pk & 0xFFFF;
      const int re_ = pk >> 16;
      const uint2 hw = *(const uint2*)(hb + (size_t)se_ * 64 + cl * 4);
      const float h0 = __uint_as_float(hw.x << 16);
      const float h1 = __uint_as_float(hw.x & 0xFFFF0000u);
      const float h2 = __uint_as_float(hw.y << 16);
      const float h3 = __uint_as_float(hw.y & 0xFFFF0000u);
      // skew: base = 4cl + 8r (&63) stays a multiple of 4 -> no wrap over +3
      const int bse = re_ * 64 + ((cl * 4 + re_ * 8) & 63);
      float* Y0 = &y0s[w][bse];
      float* Y1 = &y1s[w][bse];
      atomicAdd(&Y0[0], pe0 * h0);
      atomicAdd(&Y0[1], pe0 * h1);
      atomicAdd(&Y0[2], pe0 * h2);
      atomicAdd(&Y0[3], pe0 * h3);
      atomicAdd(&Y1[0], pe1 * h0);
      atomicAdd(&Y1[1], pe1 * h1);
      atomicAdd(&Y1[2], pe1 * h2);
      atomicAdd(&Y1[3], pe1 * h3);
    }
  }
#pragma unroll
  for (int d = 1; d < 64; d <<= 1) {
    s0 += __shfl_xor(s0, d, 64);
    s1 += __shfl_xor(s1, d, 64);
  }

  if (valid) {
    // lanes 0-31: stream 0 (mu); lanes 32-63: stream 1 (lv).
    const float* Y = (o < 32) ? y0s[w] : y1s[w];
    const int k = o & 31;  // word k holds channels (2k, 2k+1)
    const size_t nb_ = ((size_t)((o < 32) ? 0 : N) + wid) * 256;
#pragma unroll
    for (int rr = 0; rr < 8; rr++) {
      const int c0 = (2 * k + rr * 8) & 63;  // even, <=62: pair contiguous
      const float a0 = Y[rr * 64 + c0];
      const float a1 = Y[rr * 64 + c0 + 1];
      y[nb_ + rr * 32 + k] = f2bf_rne(a0) | (f2bf_rne(a1) << 16);
    }
    if (o == 0) {
      sbuf[(size_t)wid * 2 + 0] = s0;
      sbuf[(size_t)wid * 2 + 1] = s1;
    }
  }
}

// ---------------------------------------------------------------------------
// Layer-2 epilogue (R3-validated): hidden = relu(y@Wcat / s + b_conv);
// out = hidden@Wlin + b. Stage 1 MFMA (K=512), stage 2 fp32 via LDS.
// ---------------------------------------------------------------------------
__global__ __launch_bounds__(256) void out2_kernel(
    const unsigned short* __restrict__ yb,
    const unsigned short* __restrict__ Wct, const float* __restrict__ sbuf,
    const float* __restrict__ bmu, const float* __restrict__ blv,
    const float* __restrict__ Wm, const float* __restrict__ bm,
    const float* __restrict__ Wl, const float* __restrict__ bl,
    float* __restrict__ out_mu, float* __restrict__ out_ls, int N) {
  __shared__ float hstf[64][65];
  __shared__ float WL[2048];
  __shared__ float b2L[32];
  const int s = blockIdx.y;
  const int tid = threadIdx.x;
  for (int i = tid; i < 2048; i += 256) WL[i] = s ? Wl[i] : Wm[i];
  if (tid < 32) b2L[tid] = s ? bl[tid] : bm[tid];

  const int w = tid >> 6, lane = tid & 63;
  const int quad = lane >> 4, mrow = lane & 15;
  const int n0w = blockIdx.x * 64 + w * 16;
  const int gA = min(n0w + mrow, N - 1);
  const unsigned short* arow = yb + ((size_t)s * N + gA) * 512 + quad * 8;
  const unsigned short* wrow = Wct + ((size_t)s * 64 + mrow) * 512 + quad * 8;

  v4f acc[4];
#pragma unroll
  for (int tt = 0; tt < 4; tt++) acc[tt] = (v4f){0.f, 0.f, 0.f, 0.f};
#pragma unroll
  for (int k0 = 0; k0 < 512; k0 += 32) {
    v8s a = *(const v8s*)(arow + k0);
#pragma unroll
    for (int tt = 0; tt < 4; tt++) {
      v8s b = *(const v8s*)(wrow + (size_t)tt * 16 * 512 + k0);
      acc[tt] = __builtin_amdgcn_mfma_f32_16x16x32_bf16(a, b, acc[tt], 0, 0, 0);
    }
  }

  const float* bc = s ? blv : bmu;
#pragma unroll
  for (int i = 0; i < 4; i++) {
    const int node = min(n0w + quad * 4 + i, N - 1);
    const float inv = 1.f / (sbuf[(size_t)node * 2 + s] + 1e-16f);
#pragma unroll
    for (int tt = 0; tt < 4; tt++) {
      hstf[w * 16 + quad * 4 + i][tt * 16 + mrow] =
          fmaxf(acc[tt][i] * inv + bc[tt * 16 + mrow], 0.f);
    }
  }
  __syncthreads();

  const float mul = s ? 0.5f : 1.f;
  float* outp = s ? out_ls : out_mu;
  for (int idx = tid; idx < 2048; idx += 256) {
    const int nl2 = idx >> 5, oo = idx & 31;
    const int node = blockIdx.x * 64 + nl2;
    float a2 = 0.f;
#pragma unroll
    for (int c = 0; c < 64; c++) a2 = fmaf(hstf[nl2][c], WL[c * 32 + oo], a2);
    if (node < N) outp[(size_t)node * 32 + oo] = (a2 + b2L[oo]) * mul;
  }
}

// ---------------------------------------------------------------------------
extern "C" void kernel_launch(void* const* d_in, const int* in_sizes, int n_in,
                              void* d_out, int out_size, void* d_ws,
                              size_t ws_size, hipStream_t stream) {
  const float* x = (const float*)d_in[0];
  const int* edge_index = (const int*)d_in[1];
  const int* edge_type = (const int*)d_in[2];
  const float* W1 = (const float*)d_in[3];
  const float* q1 = (const float*)d_in[4];
  const float* k1 = (const float*)d_in[5];
  const float* b1 = (const float*)d_in[6];
  const float* Wmu = (const float*)d_in[7];
  const float* qmu = (const float*)d_in[8];
  const float* kmu = (const float*)d_in[9];
  const float* bmu = (const float*)d_in[10];
  const float* Wlv = (const float*)d_in[11];
  const float* qlv = (const float*)d_in[12];
  const float* klv = (const float*)d_in[13];
  const float* blv = (const float*)d_in[14];
  const float* Wm = (const float*)d_in[15];
  const float* bm = (const float*)d_in[16];
  const float* Wl = (const float*)d_in[17];
  const float* bl = (const float*)d_in[18];

  const int N = in_sizes[0] / 128;         // 50000
  const int E = in_sizes[2];               // 1.6M
  const int R = in_sizes[3] / (128 * 64);  // 8

  float* out_mu = (float*)d_out;
  float* out_ls = (float*)d_out + (size_t)N * ODIM;

  char* wsp = (char*)d_ws;
  size_t off = 0;
  auto carve = [&](size_t bytes) {
    void* p = wsp + off;
    off += (bytes + 255) & ~(size_t)255;
    return p;
  };

  // tbuf: layer-1 bf16 t (51.2 MB), then reused as y [2][N][512] bf16 (102.4)
  void* tbuf = carve((size_t)R * N * 64 * sizeof(unsigned));
  unsigned short* t1b = (unsigned short*)tbuf;
  unsigned short* yb = (unsigned short*)tbuf;
  unsigned* yw = (unsigned*)tbuf;
  unsigned short* xb = (unsigned short*)carve((size_t)N * 128 * 2);
  unsigned short* hb = (unsigned short*)carve((size_t)N * 64 * 2);
  unsigned short* W1t = (unsigned short*)carve((size_t)R * 64 * 128 * 2);
  unsigned short* Wct = (unsigned short*)carve((size_t)2 * 64 * 512 * 2);
  float* Tdir = (float*)carve((size_t)32 * 64 * sizeof(float));
  float* aq2 = (float*)carve((size_t)2 * R * N * sizeof(float));
  float* ak2 = (float*)carve((size_t)2 * R * N * sizeof(float));
  unsigned* maxk_enc = (unsigned*)carve(32 * sizeof(unsigned));
  float* sbuf = (float*)carve((size_t)N * 2 * sizeof(float));
  int* deg = (int*)carve((size_t)N * sizeof(int));
  int* row_ptr = (int*)carve((size_t)(N + 1) * sizeof(int));
  int* bsum = (int*)carve(256 * sizeof(int));
  int* cursor = (int*)carve(256 * sizeof(int));
  unsigned* tmp = (unsigned*)carve((size_t)E * sizeof(unsigned));
  int* edges = (int*)carve((size_t)E * sizeof(int));

  const int* e_src = edge_index;
  const int* e_dst = edge_index + E;

  // ---- prep: bf16 conversions + weight transposes + logit table ----
  cvt_bf16_kernel<<<(N * 128 / 4 + 255) / 256, 256, 0, stream>>>(x, xb,
                                                                 N * 128);
  transpose_w_kernel<<<24, 256, 0, stream>>>(W1, Wmu, Wlv, W1t, Wct);
  prep_T_kernel<<<1, 256, 0, stream>>>(Wmu, qmu, kmu, Wlv, qlv, klv, Tdir);

  // ---- CSR build ----
  hipMemsetAsync(deg, 0, (size_t)N * sizeof(int), stream);
  hipMemsetAsync(maxk_enc, 0, 32 * sizeof(unsigned), stream);
  count_deg_kernel<<<(E + 255) / 256, 256, 0, stream>>>(e_dst, deg, E);
  const int nchunk = (N + SCHUNK - 1) / SCHUNK;
  scan_p1<<<nchunk, 256, 0, stream>>>(deg, bsum, N);
  scan_p2<<<1, 64, 0, stream>>>(bsum, nchunk);
  scan_p3<<<nchunk, 256, 0, stream>>>(deg, bsum, row_ptr, N);

  // ---- bucketed edge placement (2-pass, no cross-XCD line sharing) ----
  const int nbuck = (N + 255) >> 8;  // 196 <= 256
  bucket_cursor_init<<<1, 256, 0, stream>>>(row_ptr, cursor, N, nbuck);
  bucket_pass1<<<(E + EPB - 1) / EPB, 256, 0, stream>>>(e_src, e_dst,
                                                        edge_type, cursor,
                                                        tmp, E);
  bucket_pass2<<<nbuck, 256, 0, stream>>>(row_ptr, tmp, edges, N);

  const int nb64 = (N + 63) / 64;
  const int agg_blocks = (N + 3) / 4;

  // ---- layer 1: IN=128 -> H=64 (MFMA, bf16 t; folded rowmax) ----
  transform1_mfma<<<dim3(R, nb64), 256, 0, stream>>>(xb, W1t, q1, k1, t1b,
                                                     aq2, ak2, maxk_enc, N);
  aggregate_kernel<<<agg_blocks, 256, 0, stream>>>(
      row_ptr, edges, t1b, aq2, ak2, maxk_enc, b1, hb, N);

  // ---- layer 2: relation-factored aggregation over h ----
  logit2_kernel<<<(N + 255) / 256, 256, 0, stream>>>(hb, Tdir, aq2, ak2,
                                                     maxk_enc + 8, N);
  aggregate2h_kernel<<<agg_blocks, 256, 0, stream>>>(
      row_ptr, edges, hb, aq2, ak2, maxk_enc + 8, yw, sbuf, N);
  out2_kernel<<<dim3(nb64, 2), 256, 0, stream>>>(yb, Wct, sbuf, bmu, blv, Wm,
                                                 bm, Wl, bl, out_mu, out_ls,
                                                 N);
}

// Round 6
// 559.049 us; speedup vs baseline: 2.8650x; 2.8650x over previous
//
#include <hip/hip_runtime.h>
#include <cstdint>

// N=50000 nodes, E=1.6M edges, IN=128, H=64, OUT=32, R=8
#define HDIM 64
#define ODIM 32
#define NEG_SLOPE 0.2f
#define SCHUNK 2048
#define EPB 8192  // edges per block in bucket_pass1

typedef __attribute__((ext_vector_type(8))) short v8s;   // 8 bf16 (4 VGPRs)
typedef __attribute__((ext_vector_type(4))) float v4f;   // MFMA accumulator

__device__ __forceinline__ unsigned f2bf_rne(float f) {
  unsigned u = __float_as_uint(f);
  return (u + 0x7FFFu + ((u >> 16) & 1u)) >> 16;  // round-to-nearest-even
}

// monotonic float<->uint order-preserving encode (for atomicMax on floats)
__device__ __forceinline__ unsigned fenc(float f) {
  unsigned u = __float_as_uint(f);
  return (u & 0x80000000u) ? ~u : (u | 0x80000000u);
}
__device__ __forceinline__ float fdec(unsigned e) {
  unsigned u = (e & 0x80000000u) ? (e ^ 0x80000000u) : ~e;
  return __uint_as_float(u);
}

// ---------------------------------------------------------------------------
// Prep: fp32 -> bf16 convert (x); weight transposes:
//   W1t [r][o][kk128] (layer-1 MFMA B), Wct [s][o][512] (out2 MFMA B).
// ---------------------------------------------------------------------------
__global__ __launch_bounds__(256) void cvt_bf16_kernel(
    const float* __restrict__ in, unsigned short* __restrict__ out, int n) {
  int i = (blockIdx.x * 256 + threadIdx.x) * 4;
  if (i + 3 < n) {
    float4 v = *(const float4*)&in[i];
    ushort4 o;
    o.x = (unsigned short)f2bf_rne(v.x);
    o.y = (unsigned short)f2bf_rne(v.y);
    o.z = (unsigned short)f2bf_rne(v.z);
    o.w = (unsigned short)f2bf_rne(v.w);
    *(ushort4*)&out[i] = o;
  }
}

__global__ __launch_bounds__(256) void transpose_w_kernel(
    const float* __restrict__ W1, const float* __restrict__ Wmu,
    const float* __restrict__ Wlv, unsigned short* __restrict__ W1t,
    unsigned short* __restrict__ Wct) {
  const int b = blockIdx.x;  // 0..23
  if (b < 8) {
    const int r = b;
    for (int idx = threadIdx.x; idx < 128 * 64; idx += 256) {
      const int kk = idx >> 6, o = idx & 63;
      W1t[((size_t)r * 64 + o) * 128 + kk] =
          (unsigned short)f2bf_rne(W1[((size_t)r * 128 + kk) * 64 + o]);
    }
  } else {
    const int s = (b - 8) >> 3, r = (b - 8) & 7;
    const float* src = s ? Wlv : Wmu;
    for (int idx = threadIdx.x; idx < 64 * 64; idx += 256) {
      const int kk = idx >> 6, o = idx & 63;
      Wct[((size_t)s * 64 + o) * 512 + r * 64 + kk] =
          (unsigned short)f2bf_rne(src[((size_t)r * 64 + kk) * 64 + o]);
    }
  }
}

// Logit direction table T[32][64] fp32:
//   T[s*8+r][c]    = sum_o W_{s,r}[c][o] * q_s[o]
//   T[16+s*8+r][c] = sum_o W_{s,r}[c][o] * k_s[o]
__global__ __launch_bounds__(256) void prep_T_kernel(
    const float* __restrict__ Wmu, const float* __restrict__ qmu,
    const float* __restrict__ kmu, const float* __restrict__ Wlv,
    const float* __restrict__ qlv, const float* __restrict__ klv,
    float* __restrict__ T) {
  for (int idx = threadIdx.x; idx < 2048; idx += 256) {
    const int j = idx >> 6, c = idx & 63;
    const int isk = j >> 4, sr = j & 15, s = sr >> 3, r = sr & 7;
    const float* W = s ? Wlv : Wmu;
    const float* vec = s ? (isk ? klv : qlv) : (isk ? kmu : qmu);
    float acc = 0.f;
    for (int o = 0; o < 64; o++)
      acc += W[((size_t)r * 64 + c) * 64 + o] * vec[o];
    T[idx] = acc;
  }
}

// ---------------------------------------------------------------------------
// CSR build over (dst, etype) keys: deg[d*8+t]; 3-phase scan (n = N*8)
// ---------------------------------------------------------------------------
__global__ __launch_bounds__(256) void count_deg_kernel(
    const int* __restrict__ dst, const int* __restrict__ etype,
    int* __restrict__ deg, int E) {
  int e = blockIdx.x * 256 + threadIdx.x;
  if (e < E) atomicAdd(&deg[dst[e] * 8 + etype[e]], 1);
}

__global__ __launch_bounds__(256) void scan_p1(const int* __restrict__ deg,
                                               int* __restrict__ bsum, int n) {
  int base = blockIdx.x * SCHUNK + threadIdx.x * 8;
  int s = 0;
#pragma unroll
  for (int j = 0; j < 8; j++) {
    int i = base + j;
    if (i < n) s += deg[i];
  }
#pragma unroll
  for (int d = 1; d < 64; d <<= 1) s += __shfl_xor(s, d, 64);
  __shared__ int ws[4];
  if ((threadIdx.x & 63) == 0) ws[threadIdx.x >> 6] = s;
  __syncthreads();
  if (threadIdx.x == 0) bsum[blockIdx.x] = ws[0] + ws[1] + ws[2] + ws[3];
}

// 256-thread exclusive scan (nb up to 256)
__global__ __launch_bounds__(256) void scan_p2(int* bsum, int nb) {
  __shared__ int wsum[4];
  const int i = threadIdx.x;
  int v = (i < nb) ? bsum[i] : 0;
  const int orig = v;
  const int lane = i & 63, w = i >> 6;
#pragma unroll
  for (int d = 1; d < 64; d <<= 1) {
    int up = __shfl_up(v, d, 64);
    if (lane >= d) v += up;
  }
  if (lane == 63) wsum[w] = v;
  __syncthreads();
  int woff = 0;
#pragma unroll
  for (int k = 0; k < 4; k++) woff += (k < w) ? wsum[k] : 0;
  if (i < nb) bsum[i] = woff + v - orig;
}

__global__ __launch_bounds__(256) void scan_p3(const int* __restrict__ deg,
                                               const int* __restrict__ bsum,
                                               int* __restrict__ row_ptr,
                                               int n) {
  int base = blockIdx.x * SCHUNK + threadIdx.x * 8;
  int vals[8];
  int s = 0;
#pragma unroll
  for (int j = 0; j < 8; j++) {
    int i = base + j;
    vals[j] = (i < n) ? deg[i] : 0;
    s += vals[j];
  }
  int lane = threadIdx.x & 63, w = threadIdx.x >> 6;
  int v = s;
#pragma unroll
  for (int d = 1; d < 64; d <<= 1) {
    int up = __shfl_up(v, d, 64);
    if (lane >= d) v += up;
  }
  __shared__ int wsum[4];
  if (lane == 63) wsum[w] = v;
  __syncthreads();
  int woff = 0;
#pragma unroll
  for (int i = 0; i < 4; i++) woff += (i < w) ? wsum[i] : 0;
  int off = bsum[blockIdx.x] + woff + v - s;
#pragma unroll
  for (int j = 0; j < 8; j++) {
    int i = base + j;
    off += vals[j];
    if (i < n) row_ptr[i + 1] = off;
  }
  if (blockIdx.x == 0 && threadIdx.x == 0) row_ptr[0] = 0;
}

// ---------------------------------------------------------------------------
// Bucketed edge placement (2-pass). Edges end up sorted by (dst, etype):
// contiguous per-(dst,r) segments via rp2 CSR (N*8+1 entries).
// ---------------------------------------------------------------------------
__global__ __launch_bounds__(256) void bucket_cursor_init(
    const int* __restrict__ rp2, int* __restrict__ cursor, int N, int nb) {
  int i = threadIdx.x;
  if (i < nb) cursor[i] = rp2[(size_t)min(i * 256, N) * 8];
}

__global__ __launch_bounds__(256) void bucket_pass1(
    const int* __restrict__ src, const int* __restrict__ dst,
    const int* __restrict__ etype, int* __restrict__ cursor,
    unsigned* __restrict__ tmp, int E) {
  __shared__ int hist[256];
  __shared__ int binstart[256];
  __shared__ int gbase[256];
  __shared__ int fill[256];
  __shared__ int wsum[4];
  __shared__ unsigned stage[EPB];
  __shared__ unsigned char binof[EPB];
  const int tid = threadIdx.x;
  const int e0 = blockIdx.x * EPB;
  const int cnt = min(EPB, E - e0);

  hist[tid] = 0;
  fill[tid] = 0;
  __syncthreads();
  for (int j = tid; j < cnt; j += 256) atomicAdd(&hist[dst[e0 + j] >> 8], 1);
  __syncthreads();

  const int hv = hist[tid];
  {
    const int lane = tid & 63, w = tid >> 6;
    int iv = hv;
#pragma unroll
    for (int d = 1; d < 64; d <<= 1) {
      int up = __shfl_up(iv, d, 64);
      if (lane >= d) iv += up;
    }
    if (lane == 63) wsum[w] = iv;
    __syncthreads();
    int woff = 0;
#pragma unroll
    for (int i = 0; i < 4; i++) woff += (i < w) ? wsum[i] : 0;
    binstart[tid] = woff + iv - hv;  // exclusive prefix
    if (hv > 0) gbase[tid] = atomicAdd(&cursor[tid], hv);
  }
  __syncthreads();

  for (int j = tid; j < cnt; j += 256) {
    const int d = dst[e0 + j];
    const int b = d >> 8;
    const unsigned rec = ((unsigned)(d & 255) << 19) |
                         ((unsigned)etype[e0 + j] << 16) |
                         (unsigned)src[e0 + j];
    const int slot = binstart[b] + atomicAdd(&fill[b], 1);
    stage[slot] = rec;
    binof[slot] = (unsigned char)b;
  }
  __syncthreads();

  for (int s = tid; s < cnt; s += 256) {
    const int b = binof[s];
    tmp[gbase[b] + (s - binstart[b])] = stage[s];
  }
}

// pass 2: one block per bucket; 2048 LDS bins (256 rows x 8 relations).
__global__ __launch_bounds__(256) void bucket_pass2(
    const int* __restrict__ rp2, const unsigned* __restrict__ tmp,
    int* __restrict__ edges, int N) {
  __shared__ int rp[2049];
  __shared__ int fill[2048];
  const int tid = threadIdx.x;
  const int rowbase = blockIdx.x * 256;
  const int rowcnt = min(256, N - rowbase);
  for (int i = tid; i <= rowcnt * 8; i += 256)
    rp[i] = rp2[(size_t)rowbase * 8 + i];
  for (int i = tid; i < 2048; i += 256) fill[i] = 0;
  __syncthreads();
  const int beg = rp[0];
  const int endv = rp[rowcnt * 8];
  for (int i = beg + tid; i < endv; i += 256) {
    const unsigned rec = tmp[i];
    const int bin = rec >> 16;  // dlow8*8 | etype3 (11 bits)
    const int pos = rp[bin] + atomicAdd(&fill[bin], 1);
    edges[pos] = (int)(rec & 0x7FFFFu);  // src | etype<<16
  }
}

// ---------------------------------------------------------------------------
// Layer-1 transform via MFMA bf16 (grid (R, nb64)) + folded rowmax.
// ---------------------------------------------------------------------------
__global__ __launch_bounds__(256) void transform1_mfma(
    const unsigned short* __restrict__ xb,
    const unsigned short* __restrict__ W1t, const float* __restrict__ q,
    const float* __restrict__ k, unsigned short* __restrict__ tb,
    float* __restrict__ aq, float* __restrict__ ak,
    unsigned* __restrict__ maxk_enc, int N) {
  __shared__ unsigned short st[4][16][72];
  __shared__ float wsm[4];
  const int r = blockIdx.x;
  const int tid = threadIdx.x;
  const int w = tid >> 6;
  const int lane = tid & 63;
  const int quad = lane >> 4;
  const int mrow = lane & 15;
  const int n0w = blockIdx.y * 64 + w * 16;

  const int gA = min(n0w + mrow, N - 1);
  const unsigned short* arow = xb + (size_t)gA * 128 + quad * 8;
  const unsigned short* wrow = W1t + ((size_t)r * 64 + mrow) * 128 + quad * 8;

  v4f acc[4];
#pragma unroll
  for (int tt = 0; tt < 4; tt++) acc[tt] = (v4f){0.f, 0.f, 0.f, 0.f};

#pragma unroll
  for (int k0 = 0; k0 < 128; k0 += 32) {
    v8s a = *(const v8s*)(arow + k0);
#pragma unroll
    for (int tt = 0; tt < 4; tt++) {
      v8s b = *(const v8s*)(wrow + (size_t)tt * 16 * 128 + k0);
      acc[tt] = __builtin_amdgcn_mfma_f32_16x16x32_bf16(a, b, acc[tt], 0, 0, 0);
    }
  }

  float qv[4], kv[4];
#pragma unroll
  for (int tt = 0; tt < 4; tt++) {
    qv[tt] = q[tt * 16 + mrow];
    kv[tt] = k[tt * 16 + mrow];
  }

  float kmax = -1e30f;
#pragma unroll
  for (int i = 0; i < 4; i++) {
    float vq = 0.f, vk = 0.f;
#pragma unroll
    for (int tt = 0; tt < 4; tt++) {
      vq = fmaf(acc[tt][i], qv[tt], vq);
      vk = fmaf(acc[tt][i], kv[tt], vk);
      st[w][quad * 4 + i][tt * 16 + mrow] =
          (unsigned short)f2bf_rne(acc[tt][i]);
    }
#pragma unroll
    for (int d = 1; d < 16; d <<= 1) {
      vq += __shfl_xor(vq, d, 64);
      vk += __shfl_xor(vk, d, 64);
    }
    kmax = fmaxf(kmax, vk);
    const int gn = n0w + quad * 4 + i;
    if (mrow == 0 && gn < N) {
      aq[(size_t)r * N + gn] = vq;
      ak[(size_t)r * N + gn] = vk;
    }
  }
#pragma unroll
  for (int d = 1; d < 64; d <<= 1) kmax = fmaxf(kmax, __shfl_xor(kmax, d, 64));
  if (lane == 0) wsm[w] = kmax;
  __syncthreads();
  if (tid == 0) {
    atomicMax(&maxk_enc[r],
              fenc(fmaxf(fmaxf(wsm[0], wsm[1]), fmaxf(wsm[2], wsm[3]))));
  }

  const int row = lane >> 2, cg = lane & 3;
  const int gns = n0w + row;
  if (gns < N) {
    const uint4 v0 = *(const uint4*)&st[w][row][cg * 16];
    const uint4 v1 = *(const uint4*)&st[w][row][cg * 16 + 8];
    uint4* dst = (uint4*)&tb[((size_t)r * N + gns) * 64 + cg * 16];
    dst[0] = v0;
    dst[1] = v1;
  }
}

// ---------------------------------------------------------------------------
// Layer-1 aggregate: R1-exact best-measured form (u-loop group gather),
// node edge range via rp2 (all 8 relation segments contiguous).
// ---------------------------------------------------------------------------
__global__ __launch_bounds__(256) void aggregate_kernel(
    const int* __restrict__ rp2, const int* __restrict__ edges,
    const unsigned short* __restrict__ tb, const float* __restrict__ aq,
    const float* __restrict__ ak, const unsigned* __restrict__ maxk_enc,
    const float* __restrict__ bias, unsigned short* __restrict__ hb, int N) {
  const int tid = threadIdx.x;
  const int w = tid >> 6, o = tid & 63;
  int wid = blockIdx.x * 4 + w;
  const bool valid = wid < N;
  if (!valid) wid = N - 1;
  const int beg = rp2[(size_t)wid * 8];
  const int end = valid ? rp2[(size_t)wid * 8 + 8] : beg;
  const int deg = end - beg;

  const float aqw = aq[(size_t)(o & 7) * N + wid];

  float v = aqw + fdec(maxk_enc[o & 7]);
  v = (v >= 0.f) ? v : NEG_SLOPE * v;
#pragma unroll
  for (int d = 1; d < 8; d <<= 1) v = fmaxf(v, __shfl_xor(v, d, 64));
  const float m = __shfl(v, 0, 64);

  const int g = o >> 3;  // edge-group 0..7 (8 edges per gather iter)
  const int cl = o & 7;  // channel lane: owns channels 8*cl .. 8*cl+7
  float s = 0.f;
  float acc[8];
#pragma unroll
  for (int c = 0; c < 8; c++) acc[c] = 0.f;

  for (int base = 0; base < deg; base += 64) {
    const int j = base + o;
    const int gcount = min(64, deg - base);
    const int packed = edges[beg + min(j, deg - 1)];
    const int src = packed & 0xFFFF;
    const int rr = packed >> 16;
    const int idx = rr * N + src;
    float x = __shfl(aqw, rr, 64) + ak[idx];
    x = (x >= 0.f) ? x : NEG_SLOPE * x;
    const float p = (j < deg) ? __expf(x - m) : 0.f;
    s += p;
    const int g8 = (gcount + 7) & ~7;
    for (int u = 0; u < g8; u += 8) {
      const int e = u + g;
      const float pe = __shfl(p, e, 64);   // 0 for padded slots
      const int ie = __shfl(idx, e, 64);   // clamped-valid index
      const uint4 tv = *(const uint4*)(tb + (size_t)ie * 64 + cl * 8);
      const unsigned uu0 = tv.x, uu1 = tv.y, uu2 = tv.z, uu3 = tv.w;
      acc[0] = fmaf(pe, __uint_as_float(uu0 << 16), acc[0]);
      acc[1] = fmaf(pe, __uint_as_float(uu0 & 0xFFFF0000u), acc[1]);
      acc[2] = fmaf(pe, __uint_as_float(uu1 << 16), acc[2]);
      acc[3] = fmaf(pe, __uint_as_float(uu1 & 0xFFFF0000u), acc[3]);
      acc[4] = fmaf(pe, __uint_as_float(uu2 << 16), acc[4]);
      acc[5] = fmaf(pe, __uint_as_float(uu2 & 0xFFFF0000u), acc[5]);
      acc[6] = fmaf(pe, __uint_as_float(uu3 << 16), acc[6]);
      acc[7] = fmaf(pe, __uint_as_float(uu3 & 0xFFFF0000u), acc[7]);
    }
  }
#pragma unroll
  for (int d = 1; d < 64; d <<= 1) s += __shfl_xor(s, d, 64);
#pragma unroll
  for (int d = 8; d < 64; d <<= 1) {
#pragma unroll
    for (int c = 0; c < 8; c++) acc[c] += __shfl_xor(acc[c], d, 64);
  }

  if (valid && g == 0) {
    const float inv = 1.f / (s + 1e-16f);
    unsigned rv[8];
#pragma unroll
    for (int c = 0; c < 8; c++) {
      const float res = acc[c] * inv + bias[cl * 8 + c];
      rv[c] = f2bf_rne(fmaxf(res, 0.f));
    }
    uint4 pkd;
    pkd.x = rv[0] | (rv[1] << 16);
    pkd.y = rv[2] | (rv[3] << 16);
    pkd.z = rv[4] | (rv[5] << 16);
    pkd.w = rv[6] | (rv[7] << 16);
    *(uint4*)(hb + (size_t)wid * 64 + cl * 8) = pkd;
  }
}

// ---------------------------------------------------------------------------
// Layer-2 logits: aq2[j,n] = h_n.T[j], ak2[j,n] = h_n.T[16+j]; folded rowmax.
// ---------------------------------------------------------------------------
__global__ __launch_bounds__(256) void logit2_kernel(
    const unsigned short* __restrict__ hb, const float* __restrict__ T,
    float* __restrict__ aq2, float* __restrict__ ak2,
    unsigned* __restrict__ maxk2_enc, int N) {
  __shared__ float Ts[2048];
  __shared__ float wred[4][16];
  for (int i = threadIdx.x; i < 2048; i += 256) Ts[i] = T[i];
  __syncthreads();
  const int n0 = blockIdx.x * 256 + threadIdx.x;
  const bool valid = n0 < N;
  const int n = valid ? n0 : N - 1;
  float h[64];
  const unsigned short* hr = hb + (size_t)n * 64;
#pragma unroll
  for (int d = 0; d < 8; d++) {
    const uint4 u = *(const uint4*)(hr + d * 8);
    h[d * 8 + 0] = __uint_as_float(u.x << 16);
    h[d * 8 + 1] = __uint_as_float(u.x & 0xFFFF0000u);
    h[d * 8 + 2] = __uint_as_float(u.y << 16);
    h[d * 8 + 3] = __uint_as_float(u.y & 0xFFFF0000u);
    h[d * 8 + 4] = __uint_as_float(u.z << 16);
    h[d * 8 + 5] = __uint_as_float(u.z & 0xFFFF0000u);
    h[d * 8 + 6] = __uint_as_float(u.w << 16);
    h[d * 8 + 7] = __uint_as_float(u.w & 0xFFFF0000u);
  }
  float kmx[16];
#pragma unroll
  for (int j = 0; j < 16; j++) {
    float dq = 0.f, dk = 0.f;
#pragma unroll
    for (int c = 0; c < 64; c++) {
      dq = fmaf(h[c], Ts[j * 64 + c], dq);
      dk = fmaf(h[c], Ts[(16 + j) * 64 + c], dk);
    }
    if (valid) {
      aq2[(size_t)j * N + n] = dq;
      ak2[(size_t)j * N + n] = dk;
    }
    kmx[j] = dk;  // invalid lanes carry node N-1 dup: max unaffected
  }
  const int lane = threadIdx.x & 63, w = threadIdx.x >> 6;
#pragma unroll
  for (int j = 0; j < 16; j++) {
#pragma unroll
    for (int d = 1; d < 64; d <<= 1)
      kmx[j] = fmaxf(kmx[j], __shfl_xor(kmx[j], d, 64));
    if (lane == 0) wred[w][j] = kmx[j];
  }
  __syncthreads();
  if (threadIdx.x < 16) {
    const float bm = fmaxf(fmaxf(wred[0][threadIdx.x], wred[1][threadIdx.x]),
                           fmaxf(wred[2][threadIdx.x], wred[3][threadIdx.x]));
    atomicMax(&maxk2_enc[threadIdx.x], fenc(bm));
  }
}

// ---------------------------------------------------------------------------
// Layer-2 aggregate, relation-factored, REGISTER-ONLY:
// one wave = one node; 8-lane group = one relation segment (static r!);
// lane owns 8 channels (one uint4 of the 128B h row). No LDS, no atomics,
// no cross-lane reduce for y (only the tiny softmax-sum at the end).
// Gathers from the 6.4MB L2-resident hb. Writes unnormalized
// y[s][node][r*64+ch] bf16 (coalesced, offset = 4*o words) + sums sbuf.
// ---------------------------------------------------------------------------
__global__ __launch_bounds__(256) void aggregate2g_kernel(
    const int* __restrict__ rp2, const int* __restrict__ edges,
    const unsigned short* __restrict__ hb, const float* __restrict__ aq2,
    const float* __restrict__ ak2, const unsigned* __restrict__ maxk2_enc,
    unsigned* __restrict__ y, float* __restrict__ sbuf, int N) {
  const int tid = threadIdx.x;
  const int w = tid >> 6, o = tid & 63;
  int wid = blockIdx.x * 4 + w;
  const bool valid = wid < N;
  if (!valid) wid = N - 1;

  // global upper-bound shift (same as validated R3/R5 path)
  const float aqw = aq2[(size_t)(o & 15) * N + wid];
  float v = aqw + fdec(maxk2_enc[o & 15]);
  v = (v >= 0.f) ? v : NEG_SLOPE * v;
#pragma unroll
  for (int d = 1; d < 8; d <<= 1) v = fmaxf(v, __shfl_xor(v, d, 64));
  const float m0 = __shfl(v, 0, 64);
  const float m1 = __shfl(v, 8, 64);

  const int grp = o >> 3;  // relation 0..7 (static per lane)
  const int ln = o & 7;    // channel octet: ch 8*ln .. 8*ln+7
  const float aqr0 = __shfl(aqw, grp, 64);
  const float aqr1 = __shfl(aqw, 8 + grp, 64);

  const int sb = rp2[(size_t)wid * 8 + grp];
  const int se = rp2[(size_t)wid * 8 + grp + 1];

  float acc0[8], acc1[8];
#pragma unroll
  for (int c = 0; c < 8; c++) {
    acc0[c] = 0.f;
    acc1[c] = 0.f;
  }
  float s0 = 0.f, s1 = 0.f;

  const size_t akoff0 = (size_t)grp * N;
  const size_t akoff1 = (size_t)(8 + grp) * N;
  for (int e = sb; e < se; ++e) {
    const int src = edges[e] & 0xFFFF;  // same addr across the 8-lane group
    const float akv0 = ak2[akoff0 + src];
    const float akv1 = ak2[akoff1 + src];
    const uint4 hv = *(const uint4*)(hb + (size_t)src * 64 + ln * 8);
    float x0 = aqr0 + akv0;
    float x1 = aqr1 + akv1;
    x0 = (x0 >= 0.f) ? x0 : NEG_SLOPE * x0;
    x1 = (x1 >= 0.f) ? x1 : NEG_SLOPE * x1;
    const float p0 = __expf(x0 - m0);
    const float p1 = __expf(x1 - m1);
    s0 += p0;
    s1 += p1;
    const unsigned uu0 = hv.x, uu1 = hv.y, uu2 = hv.z, uu3 = hv.w;
    const float h0 = __uint_as_float(uu0 << 16);
    const float h1 = __uint_as_float(uu0 & 0xFFFF0000u);
    const float h2 = __uint_as_float(uu1 << 16);
    const float h3 = __uint_as_float(uu1 & 0xFFFF0000u);
    const float h4 = __uint_as_float(uu2 << 16);
    const float h5 = __uint_as_float(uu2 & 0xFFFF0000u);
    const float h6 = __uint_as_float(uu3 << 16);
    const float h7 = __uint_as_float(uu3 & 0xFFFF0000u);
    acc0[0] = fmaf(p0, h0, acc0[0]);
    acc0[1] = fmaf(p0, h1, acc0[1]);
    acc0[2] = fmaf(p0, h2, acc0[2]);
    acc0[3] = fmaf(p0, h3, acc0[3]);
    acc0[4] = fmaf(p0, h4, acc0[4]);
    acc0[5] = fmaf(p0, h5, acc0[5]);
    acc0[6] = fmaf(p0, h6, acc0[6]);
    acc0[7] = fmaf(p0, h7, acc0[7]);
    acc1[0] = fmaf(p1, h0, acc1[0]);
    acc1[1] = fmaf(p1, h1, acc1[1]);
    acc1[2] = fmaf(p1, h2, acc1[2]);
    acc1[3] = fmaf(p1, h3, acc1[3]);
    acc1[4] = fmaf(p1, h4, acc1[4]);
    acc1[5] = fmaf(p1, h5, acc1[5]);
    acc1[6] = fmaf(p1, h6, acc1[6]);
    acc1[7] = fmaf(p1, h7, acc1[7]);
  }

  if (valid) {
    // element k = r*64 + ch; word j holds (2j, 2j+1); our words = 4*o .. +3
    uint4 p0w, p1w;
    p0w.x = f2bf_rne(acc0[0]) | (f2bf_rne(acc0[1]) << 16);
    p0w.y = f2bf_rne(acc0[2]) | (f2bf_rne(acc0[3]) << 16);
    p0w.z = f2bf_rne(acc0[4]) | (f2bf_rne(acc0[5]) << 16);
    p0w.w = f2bf_rne(acc0[6]) | (f2bf_rne(acc0[7]) << 16);
    p1w.x = f2bf_rne(acc1[0]) | (f2bf_rne(acc1[1]) << 16);
    p1w.y = f2bf_rne(acc1[2]) | (f2bf_rne(acc1[3]) << 16);
    p1w.z = f2bf_rne(acc1[4]) | (f2bf_rne(acc1[5]) << 16);
    p1w.w = f2bf_rne(acc1[6]) | (f2bf_rne(acc1[7]) << 16);
    *(uint4*)(y + (size_t)wid * 256 + 4 * o) = p0w;
    *(uint4*)(y + ((size_t)N + wid) * 256 + 4 * o) = p1w;
  }

  // total softmax sums: group values identical within group; xor over
  // distances 8/16/32 sums each of the 8 groups exactly once.
#pragma unroll
  for (int d = 8; d < 64; d <<= 1) {
    s0 += __shfl_xor(s0, d, 64);
    s1 += __shfl_xor(s1, d, 64);
  }
  if (valid && o == 0) {
    sbuf[(size_t)wid * 2 + 0] = s0;
    sbuf[(size_t)wid * 2 + 1] = s1;
  }
}

// ---------------------------------------------------------------------------
// Layer-2 epilogue (R3-validated): hidden = relu(y@Wcat / s + b_conv);
// out = hidden@Wlin + b. Stage 1 MFMA (K=512), stage 2 fp32 via LDS.
// ---------------------------------------------------------------------------
__global__ __launch_bounds__(256) void out2_kernel(
    const unsigned short* __restrict__ yb,
    const unsigned short* __restrict__ Wct, const float* __restrict__ sbuf,
    const float* __restrict__ bmu, const float* __restrict__ blv,
    const float* __restrict__ Wm, const float* __restrict__ bm,
    const float* __restrict__ Wl, const float* __restrict__ bl,
    float* __restrict__ out_mu, float* __restrict__ out_ls, int N) {
  __shared__ float hstf[64][65];
  __shared__ float WL[2048];
  __shared__ float b2L[32];
  const int s = blockIdx.y;
  const int tid = threadIdx.x;
  for (int i = tid; i < 2048; i += 256) WL[i] = s ? Wl[i] : Wm[i];
  if (tid < 32) b2L[tid] = s ? bl[tid] : bm[tid];

  const int w = tid >> 6, lane = tid & 63;
  const int quad = lane >> 4, mrow = lane & 15;
  const int n0w = blockIdx.x * 64 + w * 16;
  const int gA = min(n0w + mrow, N - 1);
  const unsigned short* arow = yb + ((size_t)s * N + gA) * 512 + quad * 8;
  const unsigned short* wrow = Wct + ((size_t)s * 64 + mrow) * 512 + quad * 8;

  v4f acc[4];
#pragma unroll
  for (int tt = 0; tt < 4; tt++) acc[tt] = (v4f){0.f, 0.f, 0.f, 0.f};
#pragma unroll
  for (int k0 = 0; k0 < 512; k0 += 32) {
    v8s a = *(const v8s*)(arow + k0);
#pragma unroll
    for (int tt = 0; tt < 4; tt++) {
      v8s b = *(const v8s*)(wrow + (size_t)tt * 16 * 512 + k0);
      acc[tt] = __builtin_amdgcn_mfma_f32_16x16x32_bf16(a, b, acc[tt], 0, 0, 0);
    }
  }

  const float* bc = s ? blv : bmu;
#pragma unroll
  for (int i = 0; i < 4; i++) {
    const int node = min(n0w + quad * 4 + i, N - 1);
    const float inv = 1.f / (sbuf[(size_t)node * 2 + s] + 1e-16f);
#pragma unroll
    for (int tt = 0; tt < 4; tt++) {
      hstf[w * 16 + quad * 4 + i][tt * 16 + mrow] =
          fmaxf(acc[tt][i] * inv + bc[tt * 16 + mrow], 0.f);
    }
  }
  __syncthreads();

  const float mul = s ? 0.5f : 1.f;
  float* outp = s ? out_ls : out_mu;
  for (int idx = tid; idx < 2048; idx += 256) {
    const int nl2 = idx >> 5, oo = idx & 31;
    const int node = blockIdx.x * 64 + nl2;
    float a2 = 0.f;
#pragma unroll
    for (int c = 0; c < 64; c++) a2 = fmaf(hstf[nl2][c], WL[c * 32 + oo], a2);
    if (node < N) outp[(size_t)node * 32 + oo] = (a2 + b2L[oo]) * mul;
  }
}

// ---------------------------------------------------------------------------
extern "C" void kernel_launch(void* const* d_in, const int* in_sizes, int n_in,
                              void* d_out, int out_size, void* d_ws,
                              size_t ws_size, hipStream_t stream) {
  const float* x = (const float*)d_in[0];
  const int* edge_index = (const int*)d_in[1];
  const int* edge_type = (const int*)d_in[2];
  const float* W1 = (const float*)d_in[3];
  const float* q1 = (const float*)d_in[4];
  const float* k1 = (const float*)d_in[5];
  const float* b1 = (const float*)d_in[6];
  const float* Wmu = (const float*)d_in[7];
  const float* qmu = (const float*)d_in[8];
  const float* kmu = (const float*)d_in[9];
  const float* bmu = (const float*)d_in[10];
  const float* Wlv = (const float*)d_in[11];
  const float* qlv = (const float*)d_in[12];
  const float* klv = (const float*)d_in[13];
  const float* blv = (const float*)d_in[14];
  const float* Wm = (const float*)d_in[15];
  const float* bm = (const float*)d_in[16];
  const float* Wl = (const float*)d_in[17];
  const float* bl = (const float*)d_in[18];

  const int N = in_sizes[0] / 128;         // 50000
  const int E = in_sizes[2];               // 1.6M
  const int R = in_sizes[3] / (128 * 64);  // 8

  float* out_mu = (float*)d_out;
  float* out_ls = (float*)d_out + (size_t)N * ODIM;

  char* wsp = (char*)d_ws;
  size_t off = 0;
  auto carve = [&](size_t bytes) {
    void* p = wsp + off;
    off += (bytes + 255) & ~(size_t)255;
    return p;
  };

  // tbuf: layer-1 bf16 t (51.2 MB), then reused as y [2][N][512] bf16 (102.4)
  void* tbuf = carve((size_t)R * N * 64 * sizeof(unsigned));
  unsigned short* t1b = (unsigned short*)tbuf;
  unsigned short* yb = (unsigned short*)tbuf;
  unsigned* yw = (unsigned*)tbuf;
  unsigned short* xb = (unsigned short*)carve((size_t)N * 128 * 2);
  unsigned short* hb = (unsigned short*)carve((size_t)N * 64 * 2);
  unsigned short* W1t = (unsigned short*)carve((size_t)R * 64 * 128 * 2);
  unsigned short* Wct = (unsigned short*)carve((size_t)2 * 64 * 512 * 2);
  float* Tdir = (float*)carve((size_t)32 * 64 * sizeof(float));
  float* aq2 = (float*)carve((size_t)2 * R * N * sizeof(float));
  float* ak2 = (float*)carve((size_t)2 * R * N * sizeof(float));
  unsigned* maxk_enc = (unsigned*)carve(32 * sizeof(unsigned));
  float* sbuf = (float*)carve((size_t)N * 2 * sizeof(float));
  int* deg = (int*)carve((size_t)N * 8 * sizeof(int));
  int* rp2 = (int*)carve(((size_t)N * 8 + 1) * sizeof(int));
  int* bsum = (int*)carve(256 * sizeof(int));
  int* cursor = (int*)carve(256 * sizeof(int));
  unsigned* tmp = (unsigned*)carve((size_t)E * sizeof(unsigned));
  int* edges = (int*)carve((size_t)E * sizeof(int));

  const int* e_src = edge_index;
  const int* e_dst = edge_index + E;

  // ---- prep: bf16 conversions + weight transposes + logit table ----
  cvt_bf16_kernel<<<(N * 128 / 4 + 255) / 256, 256, 0, stream>>>(x, xb,
                                                                 N * 128);
  transpose_w_kernel<<<24, 256, 0, stream>>>(W1, Wmu, Wlv, W1t, Wct);
  prep_T_kernel<<<1, 256, 0, stream>>>(Wmu, qmu, kmu, Wlv, qlv, klv, Tdir);

  // ---- CSR over (dst, etype) ----
  hipMemsetAsync(deg, 0, (size_t)N * 8 * sizeof(int), stream);
  hipMemsetAsync(maxk_enc, 0, 32 * sizeof(unsigned), stream);
  count_deg_kernel<<<(E + 255) / 256, 256, 0, stream>>>(e_dst, edge_type, deg,
                                                        E);
  const int n2 = N * 8;
  const int nchunk = (n2 + SCHUNK - 1) / SCHUNK;
  scan_p1<<<nchunk, 256, 0, stream>>>(deg, bsum, n2);
  scan_p2<<<1, 256, 0, stream>>>(bsum, nchunk);
  scan_p3<<<nchunk, 256, 0, stream>>>(deg, bsum, rp2, n2);

  // ---- bucketed edge placement -> edges sorted by (dst, r) ----
  const int nbuck = (N + 255) >> 8;  // 196 <= 256
  bucket_cursor_init<<<1, 256, 0, stream>>>(rp2, cursor, N, nbuck);
  bucket_pass1<<<(E + EPB - 1) / EPB, 256, 0, stream>>>(e_src, e_dst,
                                                        edge_type, cursor,
                                                        tmp, E);
  bucket_pass2<<<nbuck, 256, 0, stream>>>(rp2, tmp, edges, N);

  const int nb64 = (N + 63) / 64;
  const int agg_blocks = (N + 3) / 4;

  // ---- layer 1: IN=128 -> H=64 (MFMA, bf16 t; folded rowmax) ----
  transform1_mfma<<<dim3(R, nb64), 256, 0, stream>>>(xb, W1t, q1, k1, t1b,
                                                     aq2, ak2, maxk_enc, N);
  aggregate_kernel<<<agg_blocks, 256, 0, stream>>>(rp2, edges, t1b, aq2, ak2,
                                                   maxk_enc, b1, hb, N);

  // ---- layer 2: relation-factored, register-only aggregation over h ----
  logit2_kernel<<<(N + 255) / 256, 256, 0, stream>>>(hb, Tdir, aq2, ak2,
                                                     maxk_enc + 8, N);
  aggregate2g_kernel<<<agg_blocks, 256, 0, stream>>>(
      rp2, edges, hb, aq2, ak2, maxk_enc + 8, yw, sbuf, N);
  out2_kernel<<<dim3(nb64, 2), 256, 0, stream>>>(yb, Wct, sbuf, bmu, blv, Wm,
                                                 bm, Wl, bl, out_mu, out_ls,
                                                 N);
}

// Round 7
// 555.349 us; speedup vs baseline: 2.8841x; 1.0067x over previous
//
#include <hip/hip_runtime.h>
#include <cstdint>

// N=50000 nodes, E=1.6M edges, IN=128, H=64, OUT=32, R=8
#define HDIM 64
#define ODIM 32
#define NEG_SLOPE 0.2f
#define SCHUNK 2048
#define EPB 8192  // edges per block in bucket_pass1

typedef __attribute__((ext_vector_type(8))) short v8s;   // 8 bf16 (4 VGPRs)
typedef __attribute__((ext_vector_type(4))) float v4f;   // MFMA accumulator

__device__ __forceinline__ unsigned f2bf_rne(float f) {
  unsigned u = __float_as_uint(f);
  return (u + 0x7FFFu + ((u >> 16) & 1u)) >> 16;  // round-to-nearest-even
}

// monotonic float<->uint order-preserving encode (for atomicMax on floats)
__device__ __forceinline__ unsigned fenc(float f) {
  unsigned u = __float_as_uint(f);
  return (u & 0x80000000u) ? ~u : (u | 0x80000000u);
}
__device__ __forceinline__ float fdec(unsigned e) {
  unsigned u = (e & 0x80000000u) ? (e ^ 0x80000000u) : ~e;
  return __uint_as_float(u);
}

// ---------------------------------------------------------------------------
// Prep: fp32 -> bf16 convert (x); weight transposes:
//   W1t [r][o][kk128] (layer-1 MFMA B), Wct [s][o][512] (out2 MFMA B).
// ---------------------------------------------------------------------------
__global__ __launch_bounds__(256) void cvt_bf16_kernel(
    const float* __restrict__ in, unsigned short* __restrict__ out, int n) {
  int i = (blockIdx.x * 256 + threadIdx.x) * 4;
  if (i + 3 < n) {
    float4 v = *(const float4*)&in[i];
    ushort4 o;
    o.x = (unsigned short)f2bf_rne(v.x);
    o.y = (unsigned short)f2bf_rne(v.y);
    o.z = (unsigned short)f2bf_rne(v.z);
    o.w = (unsigned short)f2bf_rne(v.w);
    *(ushort4*)&out[i] = o;
  }
}

__global__ __launch_bounds__(256) void transpose_w_kernel(
    const float* __restrict__ W1, const float* __restrict__ Wmu,
    const float* __restrict__ Wlv, unsigned short* __restrict__ W1t,
    unsigned short* __restrict__ Wct) {
  const int b = blockIdx.x;  // 0..23
  if (b < 8) {
    const int r = b;
    for (int idx = threadIdx.x; idx < 128 * 64; idx += 256) {
      const int kk = idx >> 6, o = idx & 63;
      W1t[((size_t)r * 64 + o) * 128 + kk] =
          (unsigned short)f2bf_rne(W1[((size_t)r * 128 + kk) * 64 + o]);
    }
  } else {
    const int s = (b - 8) >> 3, r = (b - 8) & 7;
    const float* src = s ? Wlv : Wmu;
    for (int idx = threadIdx.x; idx < 64 * 64; idx += 256) {
      const int kk = idx >> 6, o = idx & 63;
      Wct[((size_t)s * 64 + o) * 512 + r * 64 + kk] =
          (unsigned short)f2bf_rne(src[((size_t)r * 64 + kk) * 64 + o]);
    }
  }
}

// Logit direction tables:
//   T[0..2047]    layer-2: T2[j=0..31][c=0..63]
//     T2[s*8+r][c]    = sum_o W_{s,r}[c][o] * q_s[o]
//     T2[16+s*8+r][c] = sum_o W_{s,r}[c][o] * k_s[o]
//   T[2048..4095] layer-1: T1[j=0..15][kk=0..127]
//     T1[r][kk]   = sum_c W1[r][kk][c] * q1[c]
//     T1[8+r][kk] = sum_c W1[r][kk][c] * k1[c]
__global__ __launch_bounds__(256) void prep_T_kernel(
    const float* __restrict__ W1, const float* __restrict__ q1,
    const float* __restrict__ k1, const float* __restrict__ Wmu,
    const float* __restrict__ qmu, const float* __restrict__ kmu,
    const float* __restrict__ Wlv, const float* __restrict__ qlv,
    const float* __restrict__ klv, float* __restrict__ T) {
  if (blockIdx.x == 0) {
    for (int idx = threadIdx.x; idx < 2048; idx += 256) {
      const int j = idx >> 6, c = idx & 63;
      const int isk = j >> 4, sr = j & 15, s = sr >> 3, r = sr & 7;
      const float* W = s ? Wlv : Wmu;
      const float* vec = s ? (isk ? klv : qlv) : (isk ? kmu : qmu);
      float acc = 0.f;
      for (int o = 0; o < 64; o++)
        acc += W[((size_t)r * 64 + c) * 64 + o] * vec[o];
      T[idx] = acc;
    }
  } else {
    for (int idx = threadIdx.x; idx < 2048; idx += 256) {
      const int j = idx >> 7, kk = idx & 127;
      const int isk = j >> 3, r = j & 7;
      const float* vec = isk ? k1 : q1;
      float acc = 0.f;
      for (int c = 0; c < 64; c++)
        acc += W1[((size_t)r * 128 + kk) * 64 + c] * vec[c];
      T[2048 + idx] = acc;
    }
  }
}

// ---------------------------------------------------------------------------
// CSR build over (dst, etype) keys: deg[d*8+t]; 3-phase scan (n = N*8)
// ---------------------------------------------------------------------------
__global__ __launch_bounds__(256) void count_deg_kernel(
    const int* __restrict__ dst, const int* __restrict__ etype,
    int* __restrict__ deg, int E) {
  int e = blockIdx.x * 256 + threadIdx.x;
  if (e < E) atomicAdd(&deg[dst[e] * 8 + etype[e]], 1);
}

__global__ __launch_bounds__(256) void scan_p1(const int* __restrict__ deg,
                                               int* __restrict__ bsum, int n) {
  int base = blockIdx.x * SCHUNK + threadIdx.x * 8;
  int s = 0;
#pragma unroll
  for (int j = 0; j < 8; j++) {
    int i = base + j;
    if (i < n) s += deg[i];
  }
#pragma unroll
  for (int d = 1; d < 64; d <<= 1) s += __shfl_xor(s, d, 64);
  __shared__ int ws[4];
  if ((threadIdx.x & 63) == 0) ws[threadIdx.x >> 6] = s;
  __syncthreads();
  if (threadIdx.x == 0) bsum[blockIdx.x] = ws[0] + ws[1] + ws[2] + ws[3];
}

// 256-thread exclusive scan (nb up to 256)
__global__ __launch_bounds__(256) void scan_p2(int* bsum, int nb) {
  __shared__ int wsum[4];
  const int i = threadIdx.x;
  int v = (i < nb) ? bsum[i] : 0;
  const int orig = v;
  const int lane = i & 63, w = i >> 6;
#pragma unroll
  for (int d = 1; d < 64; d <<= 1) {
    int up = __shfl_up(v, d, 64);
    if (lane >= d) v += up;
  }
  if (lane == 63) wsum[w] = v;
  __syncthreads();
  int woff = 0;
#pragma unroll
  for (int k = 0; k < 4; k++) woff += (k < w) ? wsum[k] : 0;
  if (i < nb) bsum[i] = woff + v - orig;
}

__global__ __launch_bounds__(256) void scan_p3(const int* __restrict__ deg,
                                               const int* __restrict__ bsum,
                                               int* __restrict__ row_ptr,
                                               int n) {
  int base = blockIdx.x * SCHUNK + threadIdx.x * 8;
  int vals[8];
  int s = 0;
#pragma unroll
  for (int j = 0; j < 8; j++) {
    int i = base + j;
    vals[j] = (i < n) ? deg[i] : 0;
    s += vals[j];
  }
  int lane = threadIdx.x & 63, w = threadIdx.x >> 6;
  int v = s;
#pragma unroll
  for (int d = 1; d < 64; d <<= 1) {
    int up = __shfl_up(v, d, 64);
    if (lane >= d) v += up;
  }
  __shared__ int wsum[4];
  if (lane == 63) wsum[w] = v;
  __syncthreads();
  int woff = 0;
#pragma unroll
  for (int i = 0; i < 4; i++) woff += (i < w) ? wsum[i] : 0;
  int off = bsum[blockIdx.x] + woff + v - s;
#pragma unroll
  for (int j = 0; j < 8; j++) {
    int i = base + j;
    off += vals[j];
    if (i < n) row_ptr[i + 1] = off;
  }
  if (blockIdx.x == 0 && threadIdx.x == 0) row_ptr[0] = 0;
}

// ---------------------------------------------------------------------------
// Bucketed edge placement (2-pass). Edges end up sorted by (dst, etype):
// contiguous per-(dst,r) segments via rp2 CSR (N*8+1 entries).
// ---------------------------------------------------------------------------
__global__ __launch_bounds__(256) void bucket_cursor_init(
    const int* __restrict__ rp2, int* __restrict__ cursor, int N, int nb) {
  int i = threadIdx.x;
  if (i < nb) cursor[i] = rp2[(size_t)min(i * 256, N) * 8];
}

__global__ __launch_bounds__(256) void bucket_pass1(
    const int* __restrict__ src, const int* __restrict__ dst,
    const int* __restrict__ etype, int* __restrict__ cursor,
    unsigned* __restrict__ tmp, int E) {
  __shared__ int hist[256];
  __shared__ int binstart[256];
  __shared__ int gbase[256];
  __shared__ int fill[256];
  __shared__ int wsum[4];
  __shared__ unsigned stage[EPB];
  __shared__ unsigned char binof[EPB];
  const int tid = threadIdx.x;
  const int e0 = blockIdx.x * EPB;
  const int cnt = min(EPB, E - e0);

  hist[tid] = 0;
  fill[tid] = 0;
  __syncthreads();
  for (int j = tid; j < cnt; j += 256) atomicAdd(&hist[dst[e0 + j] >> 8], 1);
  __syncthreads();

  const int hv = hist[tid];
  {
    const int lane = tid & 63, w = tid >> 6;
    int iv = hv;
#pragma unroll
    for (int d = 1; d < 64; d <<= 1) {
      int up = __shfl_up(iv, d, 64);
      if (lane >= d) iv += up;
    }
    if (lane == 63) wsum[w] = iv;
    __syncthreads();
    int woff = 0;
#pragma unroll
    for (int i = 0; i < 4; i++) woff += (i < w) ? wsum[i] : 0;
    binstart[tid] = woff + iv - hv;  // exclusive prefix
    if (hv > 0) gbase[tid] = atomicAdd(&cursor[tid], hv);
  }
  __syncthreads();

  for (int j = tid; j < cnt; j += 256) {
    const int d = dst[e0 + j];
    const int b = d >> 8;
    const unsigned rec = ((unsigned)(d & 255) << 19) |
                         ((unsigned)etype[e0 + j] << 16) |
                         (unsigned)src[e0 + j];
    const int slot = binstart[b] + atomicAdd(&fill[b], 1);
    stage[slot] = rec;
    binof[slot] = (unsigned char)b;
  }
  __syncthreads();

  for (int s = tid; s < cnt; s += 256) {
    const int b = binof[s];
    tmp[gbase[b] + (s - binstart[b])] = stage[s];
  }
}

// pass 2: one block per bucket; 2048 LDS bins (256 rows x 8 relations).
__global__ __launch_bounds__(256) void bucket_pass2(
    const int* __restrict__ rp2, const unsigned* __restrict__ tmp,
    int* __restrict__ edges, int N) {
  __shared__ int rp[2049];
  __shared__ int fill[2048];
  const int tid = threadIdx.x;
  const int rowbase = blockIdx.x * 256;
  const int rowcnt = min(256, N - rowbase);
  for (int i = tid; i <= rowcnt * 8; i += 256)
    rp[i] = rp2[(size_t)rowbase * 8 + i];
  for (int i = tid; i < 2048; i += 256) fill[i] = 0;
  __syncthreads();
  const int beg = rp[0];
  const int endv = rp[rowcnt * 8];
  for (int i = beg + tid; i < endv; i += 256) {
    const unsigned rec = tmp[i];
    const int bin = rec >> 16;  // dlow8*8 | etype3 (11 bits)
    const int pos = rp[bin] + atomicAdd(&fill[bin], 1);
    edges[pos] = (int)(rec & 0x7FFFFu);  // src | etype<<16
  }
}

// ---------------------------------------------------------------------------
// Layer-1 transform via MFMA bf16 (grid (R, nb64)), STRIPPED epilogue:
// pure {MFMA -> bf16 pack -> coalesced t-store}. Logits/rowmax moved to
// logit1_kernel (T1 directions) -- no shuffles/scatter/atomics here.
// ---------------------------------------------------------------------------
__global__ __launch_bounds__(256) void transform1_mfma(
    const unsigned short* __restrict__ xb,
    const unsigned short* __restrict__ W1t, unsigned short* __restrict__ tb,
    int N) {
  __shared__ unsigned short st[4][16][72];
  const int r = blockIdx.x;
  const int tid = threadIdx.x;
  const int w = tid >> 6;
  const int lane = tid & 63;
  const int quad = lane >> 4;
  const int mrow = lane & 15;
  const int n0w = blockIdx.y * 64 + w * 16;

  const int gA = min(n0w + mrow, N - 1);
  const unsigned short* arow = xb + (size_t)gA * 128 + quad * 8;
  const unsigned short* wrow = W1t + ((size_t)r * 64 + mrow) * 128 + quad * 8;

  v4f acc[4];
#pragma unroll
  for (int tt = 0; tt < 4; tt++) acc[tt] = (v4f){0.f, 0.f, 0.f, 0.f};

#pragma unroll
  for (int k0 = 0; k0 < 128; k0 += 32) {
    v8s a = *(const v8s*)(arow + k0);
#pragma unroll
    for (int tt = 0; tt < 4; tt++) {
      v8s b = *(const v8s*)(wrow + (size_t)tt * 16 * 128 + k0);
      acc[tt] = __builtin_amdgcn_mfma_f32_16x16x32_bf16(a, b, acc[tt], 0, 0, 0);
    }
  }

#pragma unroll
  for (int i = 0; i < 4; i++)
#pragma unroll
    for (int tt = 0; tt < 4; tt++)
      st[w][quad * 4 + i][tt * 16 + mrow] =
          (unsigned short)f2bf_rne(acc[tt][i]);
  __syncthreads();

  const int row = lane >> 2, cg = lane & 3;
  const int gns = n0w + row;
  if (gns < N) {
    const uint4 v0 = *(const uint4*)&st[w][row][cg * 16];
    const uint4 v1 = *(const uint4*)&st[w][row][cg * 16 + 8];
    uint4* dst = (uint4*)&tb[((size_t)r * N + gns) * 64 + cg * 16];
    dst[0] = v0;
    dst[1] = v1;
  }
}

// ---------------------------------------------------------------------------
// Layer-1 logits from T1 directions: aq1[r,n] = x_n.T1[r],
// ak1[r,n] = x_n.T1[8+r]; folded rowmax (clone of validated logit2).
// ---------------------------------------------------------------------------
__global__ __launch_bounds__(256) void logit1_kernel(
    const unsigned short* __restrict__ xb, const float* __restrict__ T1,
    float* __restrict__ aq1, float* __restrict__ ak1,
    unsigned* __restrict__ maxk_enc, int N) {
  __shared__ float Ts[2048];  // 16 x 128
  __shared__ float wred[4][8];
  for (int i = threadIdx.x; i < 2048; i += 256) Ts[i] = T1[i];
  __syncthreads();
  const int n0 = blockIdx.x * 256 + threadIdx.x;
  const bool valid = n0 < N;
  const int n = valid ? n0 : N - 1;
  const unsigned short* xr = xb + (size_t)n * 128;

  float dq[8], dk[8];
#pragma unroll
  for (int j = 0; j < 8; j++) {
    dq[j] = 0.f;
    dk[j] = 0.f;
  }
  for (int d = 0; d < 16; d++) {  // 8 channels per chunk
    const uint4 u = *(const uint4*)(xr + d * 8);
    float xv[8];
    xv[0] = __uint_as_float(u.x << 16);
    xv[1] = __uint_as_float(u.x & 0xFFFF0000u);
    xv[2] = __uint_as_float(u.y << 16);
    xv[3] = __uint_as_float(u.y & 0xFFFF0000u);
    xv[4] = __uint_as_float(u.z << 16);
    xv[5] = __uint_as_float(u.z & 0xFFFF0000u);
    xv[6] = __uint_as_float(u.w << 16);
    xv[7] = __uint_as_float(u.w & 0xFFFF0000u);
    const int base = d * 8;
#pragma unroll
    for (int j = 0; j < 8; j++) {
#pragma unroll
      for (int c = 0; c < 8; c++) {
        dq[j] = fmaf(xv[c], Ts[j * 128 + base + c], dq[j]);
        dk[j] = fmaf(xv[c], Ts[(8 + j) * 128 + base + c], dk[j]);
      }
    }
  }

  const int lane = threadIdx.x & 63, w = threadIdx.x >> 6;
#pragma unroll
  for (int j = 0; j < 8; j++) {
    if (valid) {
      aq1[(size_t)j * N + n] = dq[j];
      ak1[(size_t)j * N + n] = dk[j];
    }
    float kmx = dk[j];  // invalid lanes dup node N-1: max unaffected
#pragma unroll
    for (int d = 1; d < 64; d <<= 1)
      kmx = fmaxf(kmx, __shfl_xor(kmx, d, 64));
    if (lane == 0) wred[w][j] = kmx;
  }
  __syncthreads();
  if (threadIdx.x < 8) {
    const float bm = fmaxf(fmaxf(wred[0][threadIdx.x], wred[1][threadIdx.x]),
                           fmaxf(wred[2][threadIdx.x], wred[3][threadIdx.x]));
    atomicMax(&maxk_enc[threadIdx.x], fenc(bm));
  }
}

// ---------------------------------------------------------------------------
// Layer-1 aggregate: R1-exact best-measured form (u-loop group gather),
// node edge range via rp2 (all 8 relation segments contiguous).
// ---------------------------------------------------------------------------
__global__ __launch_bounds__(256) void aggregate_kernel(
    const int* __restrict__ rp2, const int* __restrict__ edges,
    const unsigned short* __restrict__ tb, const float* __restrict__ aq,
    const float* __restrict__ ak, const unsigned* __restrict__ maxk_enc,
    const float* __restrict__ bias, unsigned short* __restrict__ hb, int N) {
  const int tid = threadIdx.x;
  const int w = tid >> 6, o = tid & 63;
  int wid = blockIdx.x * 4 + w;
  const bool valid = wid < N;
  if (!valid) wid = N - 1;
  const int beg = rp2[(size_t)wid * 8];
  const int end = valid ? rp2[(size_t)wid * 8 + 8] : beg;
  const int deg = end - beg;

  const float aqw = aq[(size_t)(o & 7) * N + wid];

  float v = aqw + fdec(maxk_enc[o & 7]);
  v = (v >= 0.f) ? v : NEG_SLOPE * v;
#pragma unroll
  for (int d = 1; d < 8; d <<= 1) v = fmaxf(v, __shfl_xor(v, d, 64));
  const float m = __shfl(v, 0, 64);

  const int g = o >> 3;  // edge-group 0..7 (8 edges per gather iter)
  const int cl = o & 7;  // channel lane: owns channels 8*cl .. 8*cl+7
  float s = 0.f;
  float acc[8];
#pragma unroll
  for (int c = 0; c < 8; c++) acc[c] = 0.f;

  for (int base = 0; base < deg; base += 64) {
    const int j = base + o;
    const int gcount = min(64, deg - base);
    const int packed = edges[beg + min(j, deg - 1)];
    const int src = packed & 0xFFFF;
    const int rr = packed >> 16;
    const int idx = rr * N + src;
    float x = __shfl(aqw, rr, 64) + ak[idx];
    x = (x >= 0.f) ? x : NEG_SLOPE * x;
    const float p = (j < deg) ? __expf(x - m) : 0.f;
    s += p;
    const int g8 = (gcount + 7) & ~7;
    for (int u = 0; u < g8; u += 8) {
      const int e = u + g;
      const float pe = __shfl(p, e, 64);   // 0 for padded slots
      const int ie = __shfl(idx, e, 64);   // clamped-valid index
      const uint4 tv = *(const uint4*)(tb + (size_t)ie * 64 + cl * 8);
      const unsigned uu0 = tv.x, uu1 = tv.y, uu2 = tv.z, uu3 = tv.w;
      acc[0] = fmaf(pe, __uint_as_float(uu0 << 16), acc[0]);
      acc[1] = fmaf(pe, __uint_as_float(uu0 & 0xFFFF0000u), acc[1]);
      acc[2] = fmaf(pe, __uint_as_float(uu1 << 16), acc[2]);
      acc[3] = fmaf(pe, __uint_as_float(uu1 & 0xFFFF0000u), acc[3]);
      acc[4] = fmaf(pe, __uint_as_float(uu2 << 16), acc[4]);
      acc[5] = fmaf(pe, __uint_as_float(uu2 & 0xFFFF0000u), acc[5]);
      acc[6] = fmaf(pe, __uint_as_float(uu3 << 16), acc[6]);
      acc[7] = fmaf(pe, __uint_as_float(uu3 & 0xFFFF0000u), acc[7]);
    }
  }
#pragma unroll
  for (int d = 1; d < 64; d <<= 1) s += __shfl_xor(s, d, 64);
#pragma unroll
  for (int d = 8; d < 64; d <<= 1) {
#pragma unroll
    for (int c = 0; c < 8; c++) acc[c] += __shfl_xor(acc[c], d, 64);
  }

  if (valid && g == 0) {
    const float inv = 1.f / (s + 1e-16f);
    unsigned rv[8];
#pragma unroll
    for (int c = 0; c < 8; c++) {
      const float res = acc[c] * inv + bias[cl * 8 + c];
      rv[c] = f2bf_rne(fmaxf(res, 0.f));
    }
    uint4 pkd;
    pkd.x = rv[0] | (rv[1] << 16);
    pkd.y = rv[2] | (rv[3] << 16);
    pkd.z = rv[4] | (rv[5] << 16);
    pkd.w = rv[6] | (rv[7] << 16);
    *(uint4*)(hb + (size_t)wid * 64 + cl * 8) = pkd;
  }
}

// ---------------------------------------------------------------------------
// Layer-2 logits: aq2[j,n] = h_n.T[j], ak2[j,n] = h_n.T[16+j]; folded rowmax.
// ---------------------------------------------------------------------------
__global__ __launch_bounds__(256) void logit2_kernel(
    const unsigned short* __restrict__ hb, const float* __restrict__ T,
    float* __restrict__ aq2, float* __restrict__ ak2,
    unsigned* __restrict__ maxk2_enc, int N) {
  __shared__ float Ts[2048];
  __shared__ float wred[4][16];
  for (int i = threadIdx.x; i < 2048; i += 256) Ts[i] = T[i];
  __syncthreads();
  const int n0 = blockIdx.x * 256 + threadIdx.x;
  const bool valid = n0 < N;
  const int n = valid ? n0 : N - 1;
  float h[64];
  const unsigned short* hr = hb + (size_t)n * 64;
#pragma unroll
  for (int d = 0; d < 8; d++) {
    const uint4 u = *(const uint4*)(hr + d * 8);
    h[d * 8 + 0] = __uint_as_float(u.x << 16);
    h[d * 8 + 1] = __uint_as_float(u.x & 0xFFFF0000u);
    h[d * 8 + 2] = __uint_as_float(u.y << 16);
    h[d * 8 + 3] = __uint_as_float(u.y & 0xFFFF0000u);
    h[d * 8 + 4] = __uint_as_float(u.z << 16);
    h[d * 8 + 5] = __uint_as_float(u.z & 0xFFFF0000u);
    h[d * 8 + 6] = __uint_as_float(u.w << 16);
    h[d * 8 + 7] = __uint_as_float(u.w & 0xFFFF0000u);
  }
  float kmx[16];
#pragma unroll
  for (int j = 0; j < 16; j++) {
    float dq = 0.f, dk = 0.f;
#pragma unroll
    for (int c = 0; c < 64; c++) {
      dq = fmaf(h[c], Ts[j * 64 + c], dq);
      dk = fmaf(h[c], Ts[(16 + j) * 64 + c], dk);
    }
    if (valid) {
      aq2[(size_t)j * N + n] = dq;
      ak2[(size_t)j * N + n] = dk;
    }
    kmx[j] = dk;  // invalid lanes carry node N-1 dup: max unaffected
  }
  const int lane = threadIdx.x & 63, w = threadIdx.x >> 6;
#pragma unroll
  for (int j = 0; j < 16; j++) {
#pragma unroll
    for (int d = 1; d < 64; d <<= 1)
      kmx[j] = fmaxf(kmx[j], __shfl_xor(kmx[j], d, 64));
    if (lane == 0) wred[w][j] = kmx[j];
  }
  __syncthreads();
  if (threadIdx.x < 16) {
    const float bm = fmaxf(fmaxf(wred[0][threadIdx.x], wred[1][threadIdx.x]),
                           fmaxf(wred[2][threadIdx.x], wred[3][threadIdx.x]));
    atomicMax(&maxk2_enc[threadIdx.x], fenc(bm));
  }
}

// ---------------------------------------------------------------------------
// Layer-2 aggregate, relation-factored, REGISTER-ONLY (R6-validated):
// one wave = one node; 8-lane group = one relation segment (static r);
// lane owns 8 channels of the 128B h row. No LDS, no atomics.
// ---------------------------------------------------------------------------
__global__ __launch_bounds__(256) void aggregate2g_kernel(
    const int* __restrict__ rp2, const int* __restrict__ edges,
    const unsigned short* __restrict__ hb, const float* __restrict__ aq2,
    const float* __restrict__ ak2, const unsigned* __restrict__ maxk2_enc,
    unsigned* __restrict__ y, float* __restrict__ sbuf, int N) {
  const int tid = threadIdx.x;
  const int w = tid >> 6, o = tid & 63;
  int wid = blockIdx.x * 4 + w;
  const bool valid = wid < N;
  if (!valid) wid = N - 1;

  // global upper-bound shift (same as validated R3/R6 path)
  const float aqw = aq2[(size_t)(o & 15) * N + wid];
  float v = aqw + fdec(maxk2_enc[o & 15]);
  v = (v >= 0.f) ? v : NEG_SLOPE * v;
#pragma unroll
  for (int d = 1; d < 8; d <<= 1) v = fmaxf(v, __shfl_xor(v, d, 64));
  const float m0 = __shfl(v, 0, 64);
  const float m1 = __shfl(v, 8, 64);

  const int grp = o >> 3;  // relation 0..7 (static per lane)
  const int ln = o & 7;    // channel octet: ch 8*ln .. 8*ln+7
  const float aqr0 = __shfl(aqw, grp, 64);
  const float aqr1 = __shfl(aqw, 8 + grp, 64);

  const int sb = rp2[(size_t)wid * 8 + grp];
  const int se = rp2[(size_t)wid * 8 + grp + 1];

  float acc0[8], acc1[8];
#pragma unroll
  for (int c = 0; c < 8; c++) {
    acc0[c] = 0.f;
    acc1[c] = 0.f;
  }
  float s0 = 0.f, s1 = 0.f;

  const size_t akoff0 = (size_t)grp * N;
  const size_t akoff1 = (size_t)(8 + grp) * N;
  for (int e = sb; e < se; ++e) {
    const int src = edges[e] & 0xFFFF;  // same addr across the 8-lane group
    const float akv0 = ak2[akoff0 + src];
    const float akv1 = ak2[akoff1 + src];
    const uint4 hv = *(const uint4*)(hb + (size_t)src * 64 + ln * 8);
    float x0 = aqr0 + akv0;
    float x1 = aqr1 + akv1;
    x0 = (x0 >= 0.f) ? x0 : NEG_SLOPE * x0;
    x1 = (x1 >= 0.f) ? x1 : NEG_SLOPE * x1;
    const float p0 = __expf(x0 - m0);
    const float p1 = __expf(x1 - m1);
    s0 += p0;
    s1 += p1;
    const unsigned uu0 = hv.x, uu1 = hv.y, uu2 = hv.z, uu3 = hv.w;
    const float h0 = __uint_as_float(uu0 << 16);
    const float h1 = __uint_as_float(uu0 & 0xFFFF0000u);
    const float h2 = __uint_as_float(uu1 << 16);
    const float h3 = __uint_as_float(uu1 & 0xFFFF0000u);
    const float h4 = __uint_as_float(uu2 << 16);
    const float h5 = __uint_as_float(uu2 & 0xFFFF0000u);
    const float h6 = __uint_as_float(uu3 << 16);
    const float h7 = __uint_as_float(uu3 & 0xFFFF0000u);
    acc0[0] = fmaf(p0, h0, acc0[0]);
    acc0[1] = fmaf(p0, h1, acc0[1]);
    acc0[2] = fmaf(p0, h2, acc0[2]);
    acc0[3] = fmaf(p0, h3, acc0[3]);
    acc0[4] = fmaf(p0, h4, acc0[4]);
    acc0[5] = fmaf(p0, h5, acc0[5]);
    acc0[6] = fmaf(p0, h6, acc0[6]);
    acc0[7] = fmaf(p0, h7, acc0[7]);
    acc1[0] = fmaf(p1, h0, acc1[0]);
    acc1[1] = fmaf(p1, h1, acc1[1]);
    acc1[2] = fmaf(p1, h2, acc1[2]);
    acc1[3] = fmaf(p1, h3, acc1[3]);
    acc1[4] = fmaf(p1, h4, acc1[4]);
    acc1[5] = fmaf(p1, h5, acc1[5]);
    acc1[6] = fmaf(p1, h6, acc1[6]);
    acc1[7] = fmaf(p1, h7, acc1[7]);
  }

  if (valid) {
    // element k = r*64 + ch; word j holds (2j, 2j+1); our words = 4*o .. +3
    uint4 p0w, p1w;
    p0w.x = f2bf_rne(acc0[0]) | (f2bf_rne(acc0[1]) << 16);
    p0w.y = f2bf_rne(acc0[2]) | (f2bf_rne(acc0[3]) << 16);
    p0w.z = f2bf_rne(acc0[4]) | (f2bf_rne(acc0[5]) << 16);
    p0w.w = f2bf_rne(acc0[6]) | (f2bf_rne(acc0[7]) << 16);
    p1w.x = f2bf_rne(acc1[0]) | (f2bf_rne(acc1[1]) << 16);
    p1w.y = f2bf_rne(acc1[2]) | (f2bf_rne(acc1[3]) << 16);
    p1w.z = f2bf_rne(acc1[4]) | (f2bf_rne(acc1[5]) << 16);
    p1w.w = f2bf_rne(acc1[6]) | (f2bf_rne(acc1[7]) << 16);
    *(uint4*)(y + (size_t)wid * 256 + 4 * o) = p0w;
    *(uint4*)(y + ((size_t)N + wid) * 256 + 4 * o) = p1w;
  }

  // total softmax sums: group values identical within group; xor over
  // distances 8/16/32 sums each of the 8 groups exactly once.
#pragma unroll
  for (int d = 8; d < 64; d <<= 1) {
    s0 += __shfl_xor(s0, d, 64);
    s1 += __shfl_xor(s1, d, 64);
  }
  if (valid && o == 0) {
    sbuf[(size_t)wid * 2 + 0] = s0;
    sbuf[(size_t)wid * 2 + 1] = s1;
  }
}

// ---------------------------------------------------------------------------
// Layer-2 epilogue (validated): hidden = relu(y@Wcat / s + b_conv);
// out = hidden@Wlin + b. Stage 1 MFMA (K=512), stage 2 fp32 via LDS.
// ---------------------------------------------------------------------------
__global__ __launch_bounds__(256) void out2_kernel(
    const unsigned short* __restrict__ yb,
    const unsigned short* __restrict__ Wct, const float* __restrict__ sbuf,
    const float* __restrict__ bmu, const float* __restrict__ blv,
    const float* __restrict__ Wm, const float* __restrict__ bm,
    const float* __restrict__ Wl, const float* __restrict__ bl,
    float* __restrict__ out_mu, float* __restrict__ out_ls, int N) {
  __shared__ float hstf[64][65];
  __shared__ float WL[2048];
  __shared__ float b2L[32];
  const int s = blockIdx.y;
  const int tid = threadIdx.x;
  for (int i = tid; i < 2048; i += 256) WL[i] = s ? Wl[i] : Wm[i];
  if (tid < 32) b2L[tid] = s ? bl[tid] : bm[tid];

  const int w = tid >> 6, lane = tid & 63;
  const int quad = lane >> 4, mrow = lane & 15;
  const int n0w = blockIdx.x * 64 + w * 16;
  const int gA = min(n0w + mrow, N - 1);
  const unsigned short* arow = yb + ((size_t)s * N + gA) * 512 + quad * 8;
  const unsigned short* wrow = Wct + ((size_t)s * 64 + mrow) * 512 + quad * 8;

  v4f acc[4];
#pragma unroll
  for (int tt = 0; tt < 4; tt++) acc[tt] = (v4f){0.f, 0.f, 0.f, 0.f};
#pragma unroll
  for (int k0 = 0; k0 < 512; k0 += 32) {
    v8s a = *(const v8s*)(arow + k0);
#pragma unroll
    for (int tt = 0; tt < 4; tt++) {
      v8s b = *(const v8s*)(wrow + (size_t)tt * 16 * 512 + k0);
      acc[tt] = __builtin_amdgcn_mfma_f32_16x16x32_bf16(a, b, acc[tt], 0, 0, 0);
    }
  }

  const float* bc = s ? blv : bmu;
#pragma unroll
  for (int i = 0; i < 4; i++) {
    const int node = min(n0w + quad * 4 + i, N - 1);
    const float inv = 1.f / (sbuf[(size_t)node * 2 + s] + 1e-16f);
#pragma unroll
    for (int tt = 0; tt < 4; tt++) {
      hstf[w * 16 + quad * 4 + i][tt * 16 + mrow] =
          fmaxf(acc[tt][i] * inv + bc[tt * 16 + mrow], 0.f);
    }
  }
  __syncthreads();

  const float mul = s ? 0.5f : 1.f;
  float* outp = s ? out_ls : out_mu;
  for (int idx = tid; idx < 2048; idx += 256) {
    const int nl2 = idx >> 5, oo = idx & 31;
    const int node = blockIdx.x * 64 + nl2;
    float a2 = 0.f;
#pragma unroll
    for (int c = 0; c < 64; c++) a2 = fmaf(hstf[nl2][c], WL[c * 32 + oo], a2);
    if (node < N) outp[(size_t)node * 32 + oo] = (a2 + b2L[oo]) * mul;
  }
}

// ---------------------------------------------------------------------------
extern "C" void kernel_launch(void* const* d_in, const int* in_sizes, int n_in,
                              void* d_out, int out_size, void* d_ws,
                              size_t ws_size, hipStream_t stream) {
  const float* x = (const float*)d_in[0];
  const int* edge_index = (const int*)d_in[1];
  const int* edge_type = (const int*)d_in[2];
  const float* W1 = (const float*)d_in[3];
  const float* q1 = (const float*)d_in[4];
  const float* k1 = (const float*)d_in[5];
  const float* b1 = (const float*)d_in[6];
  const float* Wmu = (const float*)d_in[7];
  const float* qmu = (const float*)d_in[8];
  const float* kmu = (const float*)d_in[9];
  const float* bmu = (const float*)d_in[10];
  const float* Wlv = (const float*)d_in[11];
  const float* qlv = (const float*)d_in[12];
  const float* klv = (const float*)d_in[13];
  const float* blv = (const float*)d_in[14];
  const float* Wm = (const float*)d_in[15];
  const float* bm = (const float*)d_in[16];
  const float* Wl = (const float*)d_in[17];
  const float* bl = (const float*)d_in[18];

  const int N = in_sizes[0] / 128;         // 50000
  const int E = in_sizes[2];               // 1.6M
  const int R = in_sizes[3] / (128 * 64);  // 8

  float* out_mu = (float*)d_out;
  float* out_ls = (float*)d_out + (size_t)N * ODIM;

  char* wsp = (char*)d_ws;
  size_t off = 0;
  auto carve = [&](size_t bytes) {
    void* p = wsp + off;
    off += (bytes + 255) & ~(size_t)255;
    return p;
  };

  // tbuf: layer-1 bf16 t (51.2 MB), then reused as y [2][N][512] bf16 (102.4)
  void* tbuf = carve((size_t)R * N * 64 * sizeof(unsigned));
  unsigned short* t1b = (unsigned short*)tbuf;
  unsigned short* yb = (unsigned short*)tbuf;
  unsigned* yw = (unsigned*)tbuf;
  unsigned short* xb = (unsigned short*)carve((size_t)N * 128 * 2);
  unsigned short* hb = (unsigned short*)carve((size_t)N * 64 * 2);
  unsigned short* W1t = (unsigned short*)carve((size_t)R * 64 * 128 * 2);
  unsigned short* Wct = (unsigned short*)carve((size_t)2 * 64 * 512 * 2);
  float* Tdir = (float*)carve((size_t)4096 * sizeof(float));
  float* aq2 = (float*)carve((size_t)2 * R * N * sizeof(float));
  float* ak2 = (float*)carve((size_t)2 * R * N * sizeof(float));
  unsigned* maxk_enc = (unsigned*)carve(32 * sizeof(unsigned));
  float* sbuf = (float*)carve((size_t)N * 2 * sizeof(float));
  int* deg = (int*)carve((size_t)N * 8 * sizeof(int));
  int* rp2 = (int*)carve(((size_t)N * 8 + 1) * sizeof(int));
  int* bsum = (int*)carve(256 * sizeof(int));
  int* cursor = (int*)carve(256 * sizeof(int));
  unsigned* tmp = (unsigned*)carve((size_t)E * sizeof(unsigned));
  int* edges = (int*)carve((size_t)E * sizeof(int));

  const int* e_src = edge_index;
  const int* e_dst = edge_index + E;

  // ---- prep: bf16 conversions + weight transposes + logit tables ----
  cvt_bf16_kernel<<<(N * 128 / 4 + 255) / 256, 256, 0, stream>>>(x, xb,
                                                                 N * 128);
  transpose_w_kernel<<<24, 256, 0, stream>>>(W1, Wmu, Wlv, W1t, Wct);
  prep_T_kernel<<<2, 256, 0, stream>>>(W1, q1, k1, Wmu, qmu, kmu, Wlv, qlv,
                                       klv, Tdir);

  // ---- CSR over (dst, etype) ----
  hipMemsetAsync(deg, 0, (size_t)N * 8 * sizeof(int), stream);
  hipMemsetAsync(maxk_enc, 0, 32 * sizeof(unsigned), stream);
  count_deg_kernel<<<(E + 255) / 256, 256, 0, stream>>>(e_dst, edge_type, deg,
                                                        E);
  const int n2 = N * 8;
  const int nchunk = (n2 + SCHUNK - 1) / SCHUNK;
  scan_p1<<<nchunk, 256, 0, stream>>>(deg, bsum, n2);
  scan_p2<<<1, 256, 0, stream>>>(bsum, nchunk);
  scan_p3<<<nchunk, 256, 0, stream>>>(deg, bsum, rp2, n2);

  // ---- bucketed edge placement -> edges sorted by (dst, r) ----
  const int nbuck = (N + 255) >> 8;  // 196 <= 256
  bucket_cursor_init<<<1, 256, 0, stream>>>(rp2, cursor, N, nbuck);
  bucket_pass1<<<(E + EPB - 1) / EPB, 256, 0, stream>>>(e_src, e_dst,
                                                        edge_type, cursor,
                                                        tmp, E);
  bucket_pass2<<<nbuck, 256, 0, stream>>>(rp2, tmp, edges, N);

  const int nb64 = (N + 63) / 64;
  const int agg_blocks = (N + 3) / 4;

  // ---- layer 1: IN=128 -> H=64 (stripped MFMA transform + T1 logits) ----
  transform1_mfma<<<dim3(R, nb64), 256, 0, stream>>>(xb, W1t, t1b, N);
  logit1_kernel<<<(N + 255) / 256, 256, 0, stream>>>(xb, Tdir + 2048, aq2,
                                                     ak2, maxk_enc, N);
  aggregate_kernel<<<agg_blocks, 256, 0, stream>>>(rp2, edges, t1b, aq2, ak2,
                                                   maxk_enc, b1, hb, N);

  // ---- layer 2: relation-factored, register-only aggregation over h ----
  logit2_kernel<<<(N + 255) / 256, 256, 0, stream>>>(hb, Tdir, aq2, ak2,
                                                     maxk_enc + 8, N);
  aggregate2g_kernel<<<agg_blocks, 256, 0, stream>>>(
      rp2, edges, hb, aq2, ak2, maxk_enc + 8, yw, sbuf, N);
  out2_kernel<<<dim3(nb64, 2), 256, 0, stream>>>(yb, Wct, sbuf, bmu, blv, Wm,
                                                 bm, Wl, bl, out_mu, out_ls,
                                                 N);
}

// Round 8
// 554.605 us; speedup vs baseline: 2.8879x; 1.0013x over previous
//
#include <hip/hip_runtime.h>
#include <cstdint>

// N=50000 nodes, E=1.6M edges, IN=128, H=64, OUT=32, R=8
#define HDIM 64
#define ODIM 32
#define NEG_SLOPE 0.2f
#define SCHUNK 2048
#define EPB 8192  // edges per block in bucket_pass1

typedef __attribute__((ext_vector_type(8))) short v8s;   // 8 bf16 (4 VGPRs)
typedef __attribute__((ext_vector_type(4))) float v4f;   // MFMA accumulator

__device__ __forceinline__ unsigned f2bf_rne(float f) {
  unsigned u = __float_as_uint(f);
  return (u + 0x7FFFu + ((u >> 16) & 1u)) >> 16;  // round-to-nearest-even
}

// monotonic float<->uint order-preserving encode (for atomicMax on floats)
__device__ __forceinline__ unsigned fenc(float f) {
  unsigned u = __float_as_uint(f);
  return (u & 0x80000000u) ? ~u : (u | 0x80000000u);
}
__device__ __forceinline__ float fdec(unsigned e) {
  unsigned u = (e & 0x80000000u) ? (e ^ 0x80000000u) : ~e;
  return __uint_as_float(u);
}

// ---------------------------------------------------------------------------
// Prep: fp32 -> bf16 convert (x); weight transposes:
//   W1t [r][o][kk128] (layer-1 MFMA B), Wct [s][o][512] (out2 MFMA B).
// ---------------------------------------------------------------------------
__global__ __launch_bounds__(256) void cvt_bf16_kernel(
    const float* __restrict__ in, unsigned short* __restrict__ out, int n) {
  int i = (blockIdx.x * 256 + threadIdx.x) * 4;
  if (i + 3 < n) {
    float4 v = *(const float4*)&in[i];
    ushort4 o;
    o.x = (unsigned short)f2bf_rne(v.x);
    o.y = (unsigned short)f2bf_rne(v.y);
    o.z = (unsigned short)f2bf_rne(v.z);
    o.w = (unsigned short)f2bf_rne(v.w);
    *(ushort4*)&out[i] = o;
  }
}

__global__ __launch_bounds__(256) void transpose_w_kernel(
    const float* __restrict__ W1, const float* __restrict__ Wmu,
    const float* __restrict__ Wlv, unsigned short* __restrict__ W1t,
    unsigned short* __restrict__ Wct) {
  const int b = blockIdx.x;  // 0..23
  if (b < 8) {
    const int r = b;
    for (int idx = threadIdx.x; idx < 128 * 64; idx += 256) {
      const int kk = idx >> 6, o = idx & 63;
      W1t[((size_t)r * 64 + o) * 128 + kk] =
          (unsigned short)f2bf_rne(W1[((size_t)r * 128 + kk) * 64 + o]);
    }
  } else {
    const int s = (b - 8) >> 3, r = (b - 8) & 7;
    const float* src = s ? Wlv : Wmu;
    for (int idx = threadIdx.x; idx < 64 * 64; idx += 256) {
      const int kk = idx >> 6, o = idx & 63;
      Wct[((size_t)s * 64 + o) * 512 + r * 64 + kk] =
          (unsigned short)f2bf_rne(src[((size_t)r * 64 + kk) * 64 + o]);
    }
  }
}

// Logit direction tables:
//   T[0..2047]    layer-2: T2[j=0..31][c=0..63]
//     T2[s*8+r][c]    = sum_o W_{s,r}[c][o] * q_s[o]
//     T2[16+s*8+r][c] = sum_o W_{s,r}[c][o] * k_s[o]
//   T[2048..4095] layer-1: T1[j=0..15][kk=0..127]
//     T1[r][kk]   = sum_c W1[r][kk][c] * q1[c]
//     T1[8+r][kk] = sum_c W1[r][kk][c] * k1[c]
__global__ __launch_bounds__(256) void prep_T_kernel(
    const float* __restrict__ W1, const float* __restrict__ q1,
    const float* __restrict__ k1, const float* __restrict__ Wmu,
    const float* __restrict__ qmu, const float* __restrict__ kmu,
    const float* __restrict__ Wlv, const float* __restrict__ qlv,
    const float* __restrict__ klv, float* __restrict__ T) {
  if (blockIdx.x == 0) {
    for (int idx = threadIdx.x; idx < 2048; idx += 256) {
      const int j = idx >> 6, c = idx & 63;
      const int isk = j >> 4, sr = j & 15, s = sr >> 3, r = sr & 7;
      const float* W = s ? Wlv : Wmu;
      const float* vec = s ? (isk ? klv : qlv) : (isk ? kmu : qmu);
      float acc = 0.f;
      for (int o = 0; o < 64; o++)
        acc += W[((size_t)r * 64 + c) * 64 + o] * vec[o];
      T[idx] = acc;
    }
  } else {
    for (int idx = threadIdx.x; idx < 2048; idx += 256) {
      const int j = idx >> 7, kk = idx & 127;
      const int isk = j >> 3, r = j & 7;
      const float* vec = isk ? k1 : q1;
      float acc = 0.f;
      for (int c = 0; c < 64; c++)
        acc += W1[((size_t)r * 128 + kk) * 64 + c] * vec[c];
      T[2048 + idx] = acc;
    }
  }
}

// ---------------------------------------------------------------------------
// CSR build over (dst, etype) keys: deg[d*8+t]; 3-phase scan (n = N*8)
// ---------------------------------------------------------------------------
__global__ __launch_bounds__(256) void count_deg_kernel(
    const int* __restrict__ dst, const int* __restrict__ etype,
    int* __restrict__ deg, int E) {
  int e = blockIdx.x * 256 + threadIdx.x;
  if (e < E) atomicAdd(&deg[dst[e] * 8 + etype[e]], 1);
}

__global__ __launch_bounds__(256) void scan_p1(const int* __restrict__ deg,
                                               int* __restrict__ bsum, int n) {
  int base = blockIdx.x * SCHUNK + threadIdx.x * 8;
  int s = 0;
#pragma unroll
  for (int j = 0; j < 8; j++) {
    int i = base + j;
    if (i < n) s += deg[i];
  }
#pragma unroll
  for (int d = 1; d < 64; d <<= 1) s += __shfl_xor(s, d, 64);
  __shared__ int ws[4];
  if ((threadIdx.x & 63) == 0) ws[threadIdx.x >> 6] = s;
  __syncthreads();
  if (threadIdx.x == 0) bsum[blockIdx.x] = ws[0] + ws[1] + ws[2] + ws[3];
}

// 256-thread exclusive scan (nb up to 256)
__global__ __launch_bounds__(256) void scan_p2(int* bsum, int nb) {
  __shared__ int wsum[4];
  const int i = threadIdx.x;
  int v = (i < nb) ? bsum[i] : 0;
  const int orig = v;
  const int lane = i & 63, w = i >> 6;
#pragma unroll
  for (int d = 1; d < 64; d <<= 1) {
    int up = __shfl_up(v, d, 64);
    if (lane >= d) v += up;
  }
  if (lane == 63) wsum[w] = v;
  __syncthreads();
  int woff = 0;
#pragma unroll
  for (int k = 0; k < 4; k++) woff += (k < w) ? wsum[k] : 0;
  if (i < nb) bsum[i] = woff + v - orig;
}

__global__ __launch_bounds__(256) void scan_p3(const int* __restrict__ deg,
                                               const int* __restrict__ bsum,
                                               int* __restrict__ row_ptr,
                                               int n) {
  int base = blockIdx.x * SCHUNK + threadIdx.x * 8;
  int vals[8];
  int s = 0;
#pragma unroll
  for (int j = 0; j < 8; j++) {
    int i = base + j;
    vals[j] = (i < n) ? deg[i] : 0;
    s += vals[j];
  }
  int lane = threadIdx.x & 63, w = threadIdx.x >> 6;
  int v = s;
#pragma unroll
  for (int d = 1; d < 64; d <<= 1) {
    int up = __shfl_up(v, d, 64);
    if (lane >= d) v += up;
  }
  __shared__ int wsum[4];
  if (lane == 63) wsum[w] = v;
  __syncthreads();
  int woff = 0;
#pragma unroll
  for (int i = 0; i < 4; i++) woff += (i < w) ? wsum[i] : 0;
  int off = bsum[blockIdx.x] + woff + v - s;
#pragma unroll
  for (int j = 0; j < 8; j++) {
    int i = base + j;
    off += vals[j];
    if (i < n) row_ptr[i + 1] = off;
  }
  if (blockIdx.x == 0 && threadIdx.x == 0) row_ptr[0] = 0;
}

// ---------------------------------------------------------------------------
// Bucketed edge placement (2-pass). Edges end up sorted by (dst, etype):
// contiguous per-(dst,r) segments via rp2 CSR (N*8+1 entries).
// ---------------------------------------------------------------------------
__global__ __launch_bounds__(256) void bucket_cursor_init(
    const int* __restrict__ rp2, int* __restrict__ cursor, int N, int nb) {
  int i = threadIdx.x;
  if (i < nb) cursor[i] = rp2[(size_t)min(i * 256, N) * 8];
}

__global__ __launch_bounds__(256) void bucket_pass1(
    const int* __restrict__ src, const int* __restrict__ dst,
    const int* __restrict__ etype, int* __restrict__ cursor,
    unsigned* __restrict__ tmp, int E) {
  __shared__ int hist[256];
  __shared__ int binstart[256];
  __shared__ int gbase[256];
  __shared__ int fill[256];
  __shared__ int wsum[4];
  __shared__ unsigned stage[EPB];
  __shared__ unsigned char binof[EPB];
  const int tid = threadIdx.x;
  const int e0 = blockIdx.x * EPB;
  const int cnt = min(EPB, E - e0);

  hist[tid] = 0;
  fill[tid] = 0;
  __syncthreads();
  for (int j = tid; j < cnt; j += 256) atomicAdd(&hist[dst[e0 + j] >> 8], 1);
  __syncthreads();

  const int hv = hist[tid];
  {
    const int lane = tid & 63, w = tid >> 6;
    int iv = hv;
#pragma unroll
    for (int d = 1; d < 64; d <<= 1) {
      int up = __shfl_up(iv, d, 64);
      if (lane >= d) iv += up;
    }
    if (lane == 63) wsum[w] = iv;
    __syncthreads();
    int woff = 0;
#pragma unroll
    for (int i = 0; i < 4; i++) woff += (i < w) ? wsum[i] : 0;
    binstart[tid] = woff + iv - hv;  // exclusive prefix
    if (hv > 0) gbase[tid] = atomicAdd(&cursor[tid], hv);
  }
  __syncthreads();

  for (int j = tid; j < cnt; j += 256) {
    const int d = dst[e0 + j];
    const int b = d >> 8;
    const unsigned rec = ((unsigned)(d & 255) << 19) |
                         ((unsigned)etype[e0 + j] << 16) |
                         (unsigned)src[e0 + j];
    const int slot = binstart[b] + atomicAdd(&fill[b], 1);
    stage[slot] = rec;
    binof[slot] = (unsigned char)b;
  }
  __syncthreads();

  for (int s = tid; s < cnt; s += 256) {
    const int b = binof[s];
    tmp[gbase[b] + (s - binstart[b])] = stage[s];
  }
}

// pass 2: one block per bucket; 2048 LDS bins (256 rows x 8 relations).
__global__ __launch_bounds__(256) void bucket_pass2(
    const int* __restrict__ rp2, const unsigned* __restrict__ tmp,
    int* __restrict__ edges, int N) {
  __shared__ int rp[2049];
  __shared__ int fill[2048];
  const int tid = threadIdx.x;
  const int rowbase = blockIdx.x * 256;
  const int rowcnt = min(256, N - rowbase);
  for (int i = tid; i <= rowcnt * 8; i += 256)
    rp[i] = rp2[(size_t)rowbase * 8 + i];
  for (int i = tid; i < 2048; i += 256) fill[i] = 0;
  __syncthreads();
  const int beg = rp[0];
  const int endv = rp[rowcnt * 8];
  for (int i = beg + tid; i < endv; i += 256) {
    const unsigned rec = tmp[i];
    const int bin = rec >> 16;  // dlow8*8 | etype3 (11 bits)
    const int pos = rp[bin] + atomicAdd(&fill[bin], 1);
    edges[pos] = (int)(rec & 0x7FFFFu);  // src | etype<<16
  }
}

// ---------------------------------------------------------------------------
// Layer-1 transform via MFMA bf16 (grid (R, nb64)), STRIPPED epilogue:
// pure {MFMA -> bf16 pack -> coalesced t-store}.
// ---------------------------------------------------------------------------
__global__ __launch_bounds__(256) void transform1_mfma(
    const unsigned short* __restrict__ xb,
    const unsigned short* __restrict__ W1t, unsigned short* __restrict__ tb,
    int N) {
  __shared__ unsigned short st[4][16][72];
  const int r = blockIdx.x;
  const int tid = threadIdx.x;
  const int w = tid >> 6;
  const int lane = tid & 63;
  const int quad = lane >> 4;
  const int mrow = lane & 15;
  const int n0w = blockIdx.y * 64 + w * 16;

  const int gA = min(n0w + mrow, N - 1);
  const unsigned short* arow = xb + (size_t)gA * 128 + quad * 8;
  const unsigned short* wrow = W1t + ((size_t)r * 64 + mrow) * 128 + quad * 8;

  v4f acc[4];
#pragma unroll
  for (int tt = 0; tt < 4; tt++) acc[tt] = (v4f){0.f, 0.f, 0.f, 0.f};

#pragma unroll
  for (int k0 = 0; k0 < 128; k0 += 32) {
    v8s a = *(const v8s*)(arow + k0);
#pragma unroll
    for (int tt = 0; tt < 4; tt++) {
      v8s b = *(const v8s*)(wrow + (size_t)tt * 16 * 128 + k0);
      acc[tt] = __builtin_amdgcn_mfma_f32_16x16x32_bf16(a, b, acc[tt], 0, 0, 0);
    }
  }

#pragma unroll
  for (int i = 0; i < 4; i++)
#pragma unroll
    for (int tt = 0; tt < 4; tt++)
      st[w][quad * 4 + i][tt * 16 + mrow] =
          (unsigned short)f2bf_rne(acc[tt][i]);
  __syncthreads();

  const int row = lane >> 2, cg = lane & 3;
  const int gns = n0w + row;
  if (gns < N) {
    const uint4 v0 = *(const uint4*)&st[w][row][cg * 16];
    const uint4 v1 = *(const uint4*)&st[w][row][cg * 16 + 8];
    uint4* dst = (uint4*)&tb[((size_t)r * N + gns) * 64 + cg * 16];
    dst[0] = v0;
    dst[1] = v1;
  }
}

// ---------------------------------------------------------------------------
// Layer-1 logits from T1 directions: aq1[r,n] = x_n.T1[r],
// ak1[r,n] = x_n.T1[8+r]; folded rowmax (clone of validated logit2).
// ---------------------------------------------------------------------------
__global__ __launch_bounds__(256) void logit1_kernel(
    const unsigned short* __restrict__ xb, const float* __restrict__ T1,
    float* __restrict__ aq1, float* __restrict__ ak1,
    unsigned* __restrict__ maxk_enc, int N) {
  __shared__ float Ts[2048];  // 16 x 128
  __shared__ float wred[4][8];
  for (int i = threadIdx.x; i < 2048; i += 256) Ts[i] = T1[i];
  __syncthreads();
  const int n0 = blockIdx.x * 256 + threadIdx.x;
  const bool valid = n0 < N;
  const int n = valid ? n0 : N - 1;
  const unsigned short* xr = xb + (size_t)n * 128;

  float dq[8], dk[8];
#pragma unroll
  for (int j = 0; j < 8; j++) {
    dq[j] = 0.f;
    dk[j] = 0.f;
  }
  for (int d = 0; d < 16; d++) {  // 8 channels per chunk
    const uint4 u = *(const uint4*)(xr + d * 8);
    float xv[8];
    xv[0] = __uint_as_float(u.x << 16);
    xv[1] = __uint_as_float(u.x & 0xFFFF0000u);
    xv[2] = __uint_as_float(u.y << 16);
    xv[3] = __uint_as_float(u.y & 0xFFFF0000u);
    xv[4] = __uint_as_float(u.z << 16);
    xv[5] = __uint_as_float(u.z & 0xFFFF0000u);
    xv[6] = __uint_as_float(u.w << 16);
    xv[7] = __uint_as_float(u.w & 0xFFFF0000u);
    const int base = d * 8;
#pragma unroll
    for (int j = 0; j < 8; j++) {
#pragma unroll
      for (int c = 0; c < 8; c++) {
        dq[j] = fmaf(xv[c], Ts[j * 128 + base + c], dq[j]);
        dk[j] = fmaf(xv[c], Ts[(8 + j) * 128 + base + c], dk[j]);
      }
    }
  }

  const int lane = threadIdx.x & 63, w = threadIdx.x >> 6;
#pragma unroll
  for (int j = 0; j < 8; j++) {
    if (valid) {
      aq1[(size_t)j * N + n] = dq[j];
      ak1[(size_t)j * N + n] = dk[j];
    }
    float kmx = dk[j];  // invalid lanes dup node N-1: max unaffected
#pragma unroll
    for (int d = 1; d < 64; d <<= 1)
      kmx = fmaxf(kmx, __shfl_xor(kmx, d, 64));
    if (lane == 0) wred[w][j] = kmx;
  }
  __syncthreads();
  if (threadIdx.x < 8) {
    const float bm = fmaxf(fmaxf(wred[0][threadIdx.x], wred[1][threadIdx.x]),
                           fmaxf(wred[2][threadIdx.x], wred[3][threadIdx.x]));
    atomicMax(&maxk_enc[threadIdx.x], fenc(bm));
  }
}

// ---------------------------------------------------------------------------
// Layer-1 aggregate: R1-exact best-measured form (u-loop group gather),
// node edge range via rp2 (all 8 relation segments contiguous).
// ---------------------------------------------------------------------------
__global__ __launch_bounds__(256) void aggregate_kernel(
    const int* __restrict__ rp2, const int* __restrict__ edges,
    const unsigned short* __restrict__ tb, const float* __restrict__ aq,
    const float* __restrict__ ak, const unsigned* __restrict__ maxk_enc,
    const float* __restrict__ bias, unsigned short* __restrict__ hb, int N) {
  const int tid = threadIdx.x;
  const int w = tid >> 6, o = tid & 63;
  int wid = blockIdx.x * 4 + w;
  const bool valid = wid < N;
  if (!valid) wid = N - 1;
  const int beg = rp2[(size_t)wid * 8];
  const int end = valid ? rp2[(size_t)wid * 8 + 8] : beg;
  const int deg = end - beg;

  const float aqw = aq[(size_t)(o & 7) * N + wid];

  float v = aqw + fdec(maxk_enc[o & 7]);
  v = (v >= 0.f) ? v : NEG_SLOPE * v;
#pragma unroll
  for (int d = 1; d < 8; d <<= 1) v = fmaxf(v, __shfl_xor(v, d, 64));
  const float m = __shfl(v, 0, 64);

  const int g = o >> 3;  // edge-group 0..7 (8 edges per gather iter)
  const int cl = o & 7;  // channel lane: owns channels 8*cl .. 8*cl+7
  float s = 0.f;
  float acc[8];
#pragma unroll
  for (int c = 0; c < 8; c++) acc[c] = 0.f;

  for (int base = 0; base < deg; base += 64) {
    const int j = base + o;
    const int gcount = min(64, deg - base);
    const int packed = edges[beg + min(j, deg - 1)];
    const int src = packed & 0xFFFF;
    const int rr = packed >> 16;
    const int idx = rr * N + src;
    float x = __shfl(aqw, rr, 64) + ak[idx];
    x = (x >= 0.f) ? x : NEG_SLOPE * x;
    const float p = (j < deg) ? __expf(x - m) : 0.f;
    s += p;
    const int g8 = (gcount + 7) & ~7;
    for (int u = 0; u < g8; u += 8) {
      const int e = u + g;
      const float pe = __shfl(p, e, 64);   // 0 for padded slots
      const int ie = __shfl(idx, e, 64);   // clamped-valid index
      const uint4 tv = *(const uint4*)(tb + (size_t)ie * 64 + cl * 8);
      const unsigned uu0 = tv.x, uu1 = tv.y, uu2 = tv.z, uu3 = tv.w;
      acc[0] = fmaf(pe, __uint_as_float(uu0 << 16), acc[0]);
      acc[1] = fmaf(pe, __uint_as_float(uu0 & 0xFFFF0000u), acc[1]);
      acc[2] = fmaf(pe, __uint_as_float(uu1 << 16), acc[2]);
      acc[3] = fmaf(pe, __uint_as_float(uu1 & 0xFFFF0000u), acc[3]);
      acc[4] = fmaf(pe, __uint_as_float(uu2 << 16), acc[4]);
      acc[5] = fmaf(pe, __uint_as_float(uu2 & 0xFFFF0000u), acc[5]);
      acc[6] = fmaf(pe, __uint_as_float(uu3 << 16), acc[6]);
      acc[7] = fmaf(pe, __uint_as_float(uu3 & 0xFFFF0000u), acc[7]);
    }
  }
#pragma unroll
  for (int d = 1; d < 64; d <<= 1) s += __shfl_xor(s, d, 64);
#pragma unroll
  for (int d = 8; d < 64; d <<= 1) {
#pragma unroll
    for (int c = 0; c < 8; c++) acc[c] += __shfl_xor(acc[c], d, 64);
  }

  if (valid && g == 0) {
    const float inv = 1.f / (s + 1e-16f);
    unsigned rv[8];
#pragma unroll
    for (int c = 0; c < 8; c++) {
      const float res = acc[c] * inv + bias[cl * 8 + c];
      rv[c] = f2bf_rne(fmaxf(res, 0.f));
    }
    uint4 pkd;
    pkd.x = rv[0] | (rv[1] << 16);
    pkd.y = rv[2] | (rv[3] << 16);
    pkd.z = rv[4] | (rv[5] << 16);
    pkd.w = rv[6] | (rv[7] << 16);
    *(uint4*)(hb + (size_t)wid * 64 + cl * 8) = pkd;
  }
}

// ---------------------------------------------------------------------------
// Layer-2 logits: aq2[j,n] = h_n.T[j], ak2[j,n] = h_n.T[16+j]; folded rowmax.
// ---------------------------------------------------------------------------
__global__ __launch_bounds__(256) void logit2_kernel(
    const unsigned short* __restrict__ hb, const float* __restrict__ T,
    float* __restrict__ aq2, float* __restrict__ ak2,
    unsigned* __restrict__ maxk2_enc, int N) {
  __shared__ float Ts[2048];
  __shared__ float wred[4][16];
  for (int i = threadIdx.x; i < 2048; i += 256) Ts[i] = T[i];
  __syncthreads();
  const int n0 = blockIdx.x * 256 + threadIdx.x;
  const bool valid = n0 < N;
  const int n = valid ? n0 : N - 1;
  float h[64];
  const unsigned short* hr = hb + (size_t)n * 64;
#pragma unroll
  for (int d = 0; d < 8; d++) {
    const uint4 u = *(const uint4*)(hr + d * 8);
    h[d * 8 + 0] = __uint_as_float(u.x << 16);
    h[d * 8 + 1] = __uint_as_float(u.x & 0xFFFF0000u);
    h[d * 8 + 2] = __uint_as_float(u.y << 16);
    h[d * 8 + 3] = __uint_as_float(u.y & 0xFFFF0000u);
    h[d * 8 + 4] = __uint_as_float(u.z << 16);
    h[d * 8 + 5] = __uint_as_float(u.z & 0xFFFF0000u);
    h[d * 8 + 6] = __uint_as_float(u.w << 16);
    h[d * 8 + 7] = __uint_as_float(u.w & 0xFFFF0000u);
  }
  float kmx[16];
#pragma unroll
  for (int j = 0; j < 16; j++) {
    float dq = 0.f, dk = 0.f;
#pragma unroll
    for (int c = 0; c < 64; c++) {
      dq = fmaf(h[c], Ts[j * 64 + c], dq);
      dk = fmaf(h[c], Ts[(16 + j) * 64 + c], dk);
    }
    if (valid) {
      aq2[(size_t)j * N + n] = dq;
      ak2[(size_t)j * N + n] = dk;
    }
    kmx[j] = dk;  // invalid lanes carry node N-1 dup: max unaffected
  }
  const int lane = threadIdx.x & 63, w = threadIdx.x >> 6;
#pragma unroll
  for (int j = 0; j < 16; j++) {
#pragma unroll
    for (int d = 1; d < 64; d <<= 1)
      kmx[j] = fmaxf(kmx[j], __shfl_xor(kmx[j], d, 64));
    if (lane == 0) wred[w][j] = kmx[j];
  }
  __syncthreads();
  if (threadIdx.x < 16) {
    const float bm = fmaxf(fmaxf(wred[0][threadIdx.x], wred[1][threadIdx.x]),
                           fmaxf(wred[2][threadIdx.x], wred[3][threadIdx.x]));
    atomicMax(&maxk2_enc[threadIdx.x], fenc(bm));
  }
}

// ---------------------------------------------------------------------------
// Layer-2 aggregate, relation-factored, REGISTER-ONLY (R6-validated):
// one wave = one node; 8-lane group = one relation segment (static r);
// lane owns 8 channels of the 128B h row. No LDS, no atomics.
// ---------------------------------------------------------------------------
__global__ __launch_bounds__(256) void aggregate2g_kernel(
    const int* __restrict__ rp2, const int* __restrict__ edges,
    const unsigned short* __restrict__ hb, const float* __restrict__ aq2,
    const float* __restrict__ ak2, const unsigned* __restrict__ maxk2_enc,
    unsigned* __restrict__ y, float* __restrict__ sbuf, int N) {
  const int tid = threadIdx.x;
  const int w = tid >> 6, o = tid & 63;
  int wid = blockIdx.x * 4 + w;
  const bool valid = wid < N;
  if (!valid) wid = N - 1;

  // global upper-bound shift (same as validated R3/R6 path)
  const float aqw = aq2[(size_t)(o & 15) * N + wid];
  float v = aqw + fdec(maxk2_enc[o & 15]);
  v = (v >= 0.f) ? v : NEG_SLOPE * v;
#pragma unroll
  for (int d = 1; d < 8; d <<= 1) v = fmaxf(v, __shfl_xor(v, d, 64));
  const float m0 = __shfl(v, 0, 64);
  const float m1 = __shfl(v, 8, 64);

  const int grp = o >> 3;  // relation 0..7 (static per lane)
  const int ln = o & 7;    // channel octet: ch 8*ln .. 8*ln+7
  const float aqr0 = __shfl(aqw, grp, 64);
  const float aqr1 = __shfl(aqw, 8 + grp, 64);

  const int sb = rp2[(size_t)wid * 8 + grp];
  const int se = rp2[(size_t)wid * 8 + grp + 1];

  float acc0[8], acc1[8];
#pragma unroll
  for (int c = 0; c < 8; c++) {
    acc0[c] = 0.f;
    acc1[c] = 0.f;
  }
  float s0 = 0.f, s1 = 0.f;

  const size_t akoff0 = (size_t)grp * N;
  const size_t akoff1 = (size_t)(8 + grp) * N;
  for (int e = sb; e < se; ++e) {
    const int src = edges[e] & 0xFFFF;  // same addr across the 8-lane group
    const float akv0 = ak2[akoff0 + src];
    const float akv1 = ak2[akoff1 + src];
    const uint4 hv = *(const uint4*)(hb + (size_t)src * 64 + ln * 8);
    float x0 = aqr0 + akv0;
    float x1 = aqr1 + akv1;
    x0 = (x0 >= 0.f) ? x0 : NEG_SLOPE * x0;
    x1 = (x1 >= 0.f) ? x1 : NEG_SLOPE * x1;
    const float p0 = __expf(x0 - m0);
    const float p1 = __expf(x1 - m1);
    s0 += p0;
    s1 += p1;
    const unsigned uu0 = hv.x, uu1 = hv.y, uu2 = hv.z, uu3 = hv.w;
    const float h0 = __uint_as_float(uu0 << 16);
    const float h1 = __uint_as_float(uu0 & 0xFFFF0000u);
    const float h2 = __uint_as_float(uu1 << 16);
    const float h3 = __uint_as_float(uu1 & 0xFFFF0000u);
    const float h4 = __uint_as_float(uu2 << 16);
    const float h5 = __uint_as_float(uu2 & 0xFFFF0000u);
    const float h6 = __uint_as_float(uu3 << 16);
    const float h7 = __uint_as_float(uu3 & 0xFFFF0000u);
    acc0[0] = fmaf(p0, h0, acc0[0]);
    acc0[1] = fmaf(p0, h1, acc0[1]);
    acc0[2] = fmaf(p0, h2, acc0[2]);
    acc0[3] = fmaf(p0, h3, acc0[3]);
    acc0[4] = fmaf(p0, h4, acc0[4]);
    acc0[5] = fmaf(p0, h5, acc0[5]);
    acc0[6] = fmaf(p0, h6, acc0[6]);
    acc0[7] = fmaf(p0, h7, acc0[7]);
    acc1[0] = fmaf(p1, h0, acc1[0]);
    acc1[1] = fmaf(p1, h1, acc1[1]);
    acc1[2] = fmaf(p1, h2, acc1[2]);
    acc1[3] = fmaf(p1, h3, acc1[3]);
    acc1[4] = fmaf(p1, h4, acc1[4]);
    acc1[5] = fmaf(p1, h5, acc1[5]);
    acc1[6] = fmaf(p1, h6, acc1[6]);
    acc1[7] = fmaf(p1, h7, acc1[7]);
  }

  if (valid) {
    // element k = r*64 + ch; word j holds (2j, 2j+1); our words = 4*o .. +3
    uint4 p0w, p1w;
    p0w.x = f2bf_rne(acc0[0]) | (f2bf_rne(acc0[1]) << 16);
    p0w.y = f2bf_rne(acc0[2]) | (f2bf_rne(acc0[3]) << 16);
    p0w.z = f2bf_rne(acc0[4]) | (f2bf_rne(acc0[5]) << 16);
    p0w.w = f2bf_rne(acc0[6]) | (f2bf_rne(acc0[7]) << 16);
    p1w.x = f2bf_rne(acc1[0]) | (f2bf_rne(acc1[1]) << 16);
    p1w.y = f2bf_rne(acc1[2]) | (f2bf_rne(acc1[3]) << 16);
    p1w.z = f2bf_rne(acc1[4]) | (f2bf_rne(acc1[5]) << 16);
    p1w.w = f2bf_rne(acc1[6]) | (f2bf_rne(acc1[7]) << 16);
    *(uint4*)(y + (size_t)wid * 256 + 4 * o) = p0w;
    *(uint4*)(y + ((size_t)N + wid) * 256 + 4 * o) = p1w;
  }

  // total softmax sums: group values identical within group; xor over
  // distances 8/16/32 sums each of the 8 groups exactly once.
#pragma unroll
  for (int d = 8; d < 64; d <<= 1) {
    s0 += __shfl_xor(s0, d, 64);
    s1 += __shfl_xor(s1, d, 64);
  }
  if (valid && o == 0) {
    sbuf[(size_t)wid * 2 + 0] = s0;
    sbuf[(size_t)wid * 2 + 1] = s1;
  }
}

// ---------------------------------------------------------------------------
// Layer-2 epilogue: hidden = relu(y@Wcat / s + b_conv); out = hidden@Wlin+b.
// Stage 1 MFMA (K=512) with FULL A-prefetch (16x uint4 -> one latency
// exposure instead of ~16 serialized waits at VGPR 56), stage 2 fp32 via LDS.
// ---------------------------------------------------------------------------
__global__ __launch_bounds__(256) void out2_kernel(
    const unsigned short* __restrict__ yb,
    const unsigned short* __restrict__ Wct, const float* __restrict__ sbuf,
    const float* __restrict__ bmu, const float* __restrict__ blv,
    const float* __restrict__ Wm, const float* __restrict__ bm,
    const float* __restrict__ Wl, const float* __restrict__ bl,
    float* __restrict__ out_mu, float* __restrict__ out_ls, int N) {
  __shared__ float hstf[64][65];
  __shared__ float WL[2048];
  __shared__ float b2L[32];
  const int s = blockIdx.y;
  const int tid = threadIdx.x;

  const int w = tid >> 6, lane = tid & 63;
  const int quad = lane >> 4, mrow = lane & 15;
  const int n0w = blockIdx.x * 64 + w * 16;
  const int gA = min(n0w + mrow, N - 1);
  const unsigned short* arow = yb + ((size_t)s * N + gA) * 512 + quad * 8;
  const unsigned short* wrow = Wct + ((size_t)s * 64 + mrow) * 512 + quad * 8;

  // issue ALL 16 A-fragment loads (256B/lane) before anything else; the
  // WL staging below + B loads overlap their latency.
  v8s a[16];
#pragma unroll
  for (int k = 0; k < 16; k++) a[k] = *(const v8s*)(arow + k * 32);

  for (int i = tid; i < 2048; i += 256) WL[i] = s ? Wl[i] : Wm[i];
  if (tid < 32) b2L[tid] = s ? bl[tid] : bm[tid];

  v4f acc[4];
#pragma unroll
  for (int tt = 0; tt < 4; tt++) acc[tt] = (v4f){0.f, 0.f, 0.f, 0.f};
#pragma unroll
  for (int k = 0; k < 16; k++) {
#pragma unroll
    for (int tt = 0; tt < 4; tt++) {
      v8s b = *(const v8s*)(wrow + (size_t)tt * 16 * 512 + k * 32);
      acc[tt] = __builtin_amdgcn_mfma_f32_16x16x32_bf16(a[k], b, acc[tt], 0,
                                                        0, 0);
    }
  }

  const float* bc = s ? blv : bmu;
#pragma unroll
  for (int i = 0; i < 4; i++) {
    const int node = min(n0w + quad * 4 + i, N - 1);
    const float inv = 1.f / (sbuf[(size_t)node * 2 + s] + 1e-16f);
#pragma unroll
    for (int tt = 0; tt < 4; tt++) {
      hstf[w * 16 + quad * 4 + i][tt * 16 + mrow] =
          fmaxf(acc[tt][i] * inv + bc[tt * 16 + mrow], 0.f);
    }
  }
  __syncthreads();

  const float mul = s ? 0.5f : 1.f;
  float* outp = s ? out_ls : out_mu;
  for (int idx = tid; idx < 2048; idx += 256) {
    const int nl2 = idx >> 5, oo = idx & 31;
    const int node = blockIdx.x * 64 + nl2;
    float a2 = 0.f;
#pragma unroll
    for (int c = 0; c < 64; c++) a2 = fmaf(hstf[nl2][c], WL[c * 32 + oo], a2);
    if (node < N) outp[(size_t)node * 32 + oo] = (a2 + b2L[oo]) * mul;
  }
}

// ---------------------------------------------------------------------------
extern "C" void kernel_launch(void* const* d_in, const int* in_sizes, int n_in,
                              void* d_out, int out_size, void* d_ws,
                              size_t ws_size, hipStream_t stream) {
  const float* x = (const float*)d_in[0];
  const int* edge_index = (const int*)d_in[1];
  const int* edge_type = (const int*)d_in[2];
  const float* W1 = (const float*)d_in[3];
  const float* q1 = (const float*)d_in[4];
  const float* k1 = (const float*)d_in[5];
  const float* b1 = (const float*)d_in[6];
  const float* Wmu = (const float*)d_in[7];
  const float* qmu = (const float*)d_in[8];
  const float* kmu = (const float*)d_in[9];
  const float* bmu = (const float*)d_in[10];
  const float* Wlv = (const float*)d_in[11];
  const float* qlv = (const float*)d_in[12];
  const float* klv = (const float*)d_in[13];
  const float* blv = (const float*)d_in[14];
  const float* Wm = (const float*)d_in[15];
  const float* bm = (const float*)d_in[16];
  const float* Wl = (const float*)d_in[17];
  const float* bl = (const float*)d_in[18];

  const int N = in_sizes[0] / 128;         // 50000
  const int E = in_sizes[2];               // 1.6M
  const int R = in_sizes[3] / (128 * 64);  // 8

  float* out_mu = (float*)d_out;
  float* out_ls = (float*)d_out + (size_t)N * ODIM;

  char* wsp = (char*)d_ws;
  size_t off = 0;
  auto carve = [&](size_t bytes) {
    void* p = wsp + off;
    off += (bytes + 255) & ~(size_t)255;
    return p;
  };

  // tbuf: layer-1 bf16 t (51.2 MB), then reused as y [2][N][512] bf16 (102.4)
  void* tbuf = carve((size_t)R * N * 64 * sizeof(unsigned));
  unsigned short* t1b = (unsigned short*)tbuf;
  unsigned short* yb = (unsigned short*)tbuf;
  unsigned* yw = (unsigned*)tbuf;
  unsigned short* xb = (unsigned short*)carve((size_t)N * 128 * 2);
  unsigned short* hb = (unsigned short*)carve((size_t)N * 64 * 2);
  unsigned short* W1t = (unsigned short*)carve((size_t)R * 64 * 128 * 2);
  unsigned short* Wct = (unsigned short*)carve((size_t)2 * 64 * 512 * 2);
  float* Tdir = (float*)carve((size_t)4096 * sizeof(float));
  float* aq2 = (float*)carve((size_t)2 * R * N * sizeof(float));
  float* ak2 = (float*)carve((size_t)2 * R * N * sizeof(float));
  unsigned* maxk_enc = (unsigned*)carve(32 * sizeof(unsigned));
  float* sbuf = (float*)carve((size_t)N * 2 * sizeof(float));
  int* deg = (int*)carve((size_t)N * 8 * sizeof(int));
  int* rp2 = (int*)carve(((size_t)N * 8 + 1) * sizeof(int));
  int* bsum = (int*)carve(256 * sizeof(int));
  int* cursor = (int*)carve(256 * sizeof(int));
  unsigned* tmp = (unsigned*)carve((size_t)E * sizeof(unsigned));
  int* edges = (int*)carve((size_t)E * sizeof(int));

  const int* e_src = edge_index;
  const int* e_dst = edge_index + E;

  // ---- prep: bf16 conversions + weight transposes + logit tables ----
  cvt_bf16_kernel<<<(N * 128 / 4 + 255) / 256, 256, 0, stream>>>(x, xb,
                                                                 N * 128);
  transpose_w_kernel<<<24, 256, 0, stream>>>(W1, Wmu, Wlv, W1t, Wct);
  prep_T_kernel<<<2, 256, 0, stream>>>(W1, q1, k1, Wmu, qmu, kmu, Wlv, qlv,
                                       klv, Tdir);

  // ---- CSR over (dst, etype) ----
  hipMemsetAsync(deg, 0, (size_t)N * 8 * sizeof(int), stream);
  hipMemsetAsync(maxk_enc, 0, 32 * sizeof(unsigned), stream);
  count_deg_kernel<<<(E + 255) / 256, 256, 0, stream>>>(e_dst, edge_type, deg,
                                                        E);
  const int n2 = N * 8;
  const int nchunk = (n2 + SCHUNK - 1) / SCHUNK;
  scan_p1<<<nchunk, 256, 0, stream>>>(deg, bsum, n2);
  scan_p2<<<1, 256, 0, stream>>>(bsum, nchunk);
  scan_p3<<<nchunk, 256, 0, stream>>>(deg, bsum, rp2, n2);

  // ---- bucketed edge placement -> edges sorted by (dst, r) ----
  const int nbuck = (N + 255) >> 8;  // 196 <= 256
  bucket_cursor_init<<<1, 256, 0, stream>>>(rp2, cursor, N, nbuck);
  bucket_pass1<<<(E + EPB - 1) / EPB, 256, 0, stream>>>(e_src, e_dst,
                                                        edge_type, cursor,
                                                        tmp, E);
  bucket_pass2<<<nbuck, 256, 0, stream>>>(rp2, tmp, edges, N);

  const int nb64 = (N + 63) / 64;
  const int agg_blocks = (N + 3) / 4;

  // ---- layer 1: IN=128 -> H=64 (stripped MFMA transform + T1 logits) ----
  transform1_mfma<<<dim3(R, nb64), 256, 0, stream>>>(xb, W1t, t1b, N);
  logit1_kernel<<<(N + 255) / 256, 256, 0, stream>>>(xb, Tdir + 2048, aq2,
                                                     ak2, maxk_enc, N);
  aggregate_kernel<<<agg_blocks, 256, 0, stream>>>(rp2, edges, t1b, aq2, ak2,
                                                   maxk_enc, b1, hb, N);

  // ---- layer 2: relation-factored, register-only aggregation over h ----
  logit2_kernel<<<(N + 255) / 256, 256, 0, stream>>>(hb, Tdir, aq2, ak2,
                                                     maxk_enc + 8, N);
  aggregate2g_kernel<<<agg_blocks, 256, 0, stream>>>(
      rp2, edges, hb, aq2, ak2, maxk_enc + 8, yw, sbuf, N);
  out2_kernel<<<dim3(nb64, 2), 256, 0, stream>>>(yb, Wct, sbuf, bmu, blv, Wm,
                                                 bm, Wl, bl, out_mu, out_ls,
                                                 N);
}

// Round 9
// 547.943 us; speedup vs baseline: 2.9231x; 1.0122x over previous
//
#include <hip/hip_runtime.h>
#include <cstdint>

// N=50000 nodes, E=1.6M edges, IN=128, H=64, OUT=32, R=8
#define HDIM 64
#define ODIM 32
#define NEG_SLOPE 0.2f
#define SCHUNK 2048
#define EPB 8192  // edges per block in bucket_pass1

typedef __attribute__((ext_vector_type(8))) short v8s;   // 8 bf16 (4 VGPRs)
typedef __attribute__((ext_vector_type(4))) float v4f;   // MFMA accumulator

__device__ __forceinline__ unsigned f2bf_rne(float f) {
  unsigned u = __float_as_uint(f);
  return (u + 0x7FFFu + ((u >> 16) & 1u)) >> 16;  // round-to-nearest-even
}

// monotonic float<->uint order-preserving encode (for atomicMax on floats)
__device__ __forceinline__ unsigned fenc(float f) {
  unsigned u = __float_as_uint(f);
  return (u & 0x80000000u) ? ~u : (u | 0x80000000u);
}
__device__ __forceinline__ float fdec(unsigned e) {
  unsigned u = (e & 0x80000000u) ? (e ^ 0x80000000u) : ~e;
  return __uint_as_float(u);
}

// ---------------------------------------------------------------------------
// Prep: fp32 -> bf16 convert (x); weight transposes:
//   W1t  [r][o][kk128] (layer-1 MFMA B)
//   Wct  [s][o][512]   (out2 stage-1 MFMA B)
//   Wlt2 [s][o32][c64] (out2 stage-2 MFMA B: transposed final linears)
// ---------------------------------------------------------------------------
__global__ __launch_bounds__(256) void cvt_bf16_kernel(
    const float* __restrict__ in, unsigned short* __restrict__ out, int n) {
  int i = (blockIdx.x * 256 + threadIdx.x) * 4;
  if (i + 3 < n) {
    float4 v = *(const float4*)&in[i];
    ushort4 o;
    o.x = (unsigned short)f2bf_rne(v.x);
    o.y = (unsigned short)f2bf_rne(v.y);
    o.z = (unsigned short)f2bf_rne(v.z);
    o.w = (unsigned short)f2bf_rne(v.w);
    *(ushort4*)&out[i] = o;
  }
}

__global__ __launch_bounds__(256) void transpose_w_kernel(
    const float* __restrict__ W1, const float* __restrict__ Wmu,
    const float* __restrict__ Wlv, const float* __restrict__ Wm,
    const float* __restrict__ Wl, unsigned short* __restrict__ W1t,
    unsigned short* __restrict__ Wct, unsigned short* __restrict__ Wlt2) {
  const int b = blockIdx.x;  // 0..25
  if (b < 8) {
    const int r = b;
    for (int idx = threadIdx.x; idx < 128 * 64; idx += 256) {
      const int kk = idx >> 6, o = idx & 63;
      W1t[((size_t)r * 64 + o) * 128 + kk] =
          (unsigned short)f2bf_rne(W1[((size_t)r * 128 + kk) * 64 + o]);
    }
  } else if (b < 24) {
    const int s = (b - 8) >> 3, r = (b - 8) & 7;
    const float* src = s ? Wlv : Wmu;
    for (int idx = threadIdx.x; idx < 64 * 64; idx += 256) {
      const int kk = idx >> 6, o = idx & 63;
      Wct[((size_t)s * 64 + o) * 512 + r * 64 + kk] =
          (unsigned short)f2bf_rne(src[((size_t)r * 64 + kk) * 64 + o]);
    }
  } else {
    const int s = b - 24;
    const float* src = s ? Wl : Wm;  // [c=64][o=32] row-major
    for (int idx = threadIdx.x; idx < 32 * 64; idx += 256) {
      const int o = idx >> 6, c = idx & 63;
      Wlt2[((size_t)s * 32 + o) * 64 + c] =
          (unsigned short)f2bf_rne(src[(size_t)c * 32 + o]);
    }
  }
}

// Logit direction tables:
//   T[0..2047]    layer-2: T2[j=0..31][c=0..63]
//   T[2048..4095] layer-1: T1[j=0..15][kk=0..127]
__global__ __launch_bounds__(256) void prep_T_kernel(
    const float* __restrict__ W1, const float* __restrict__ q1,
    const float* __restrict__ k1, const float* __restrict__ Wmu,
    const float* __restrict__ qmu, const float* __restrict__ kmu,
    const float* __restrict__ Wlv, const float* __restrict__ qlv,
    const float* __restrict__ klv, float* __restrict__ T) {
  if (blockIdx.x == 0) {
    for (int idx = threadIdx.x; idx < 2048; idx += 256) {
      const int j = idx >> 6, c = idx & 63;
      const int isk = j >> 4, sr = j & 15, s = sr >> 3, r = sr & 7;
      const float* W = s ? Wlv : Wmu;
      const float* vec = s ? (isk ? klv : qlv) : (isk ? kmu : qmu);
      float acc = 0.f;
      for (int o = 0; o < 64; o++)
        acc += W[((size_t)r * 64 + c) * 64 + o] * vec[o];
      T[idx] = acc;
    }
  } else {
    for (int idx = threadIdx.x; idx < 2048; idx += 256) {
      const int j = idx >> 7, kk = idx & 127;
      const int isk = j >> 3, r = j & 7;
      const float* vec = isk ? k1 : q1;
      float acc = 0.f;
      for (int c = 0; c < 64; c++)
        acc += W1[((size_t)r * 128 + kk) * 64 + c] * vec[c];
      T[2048 + idx] = acc;
    }
  }
}

// ---------------------------------------------------------------------------
// CSR build over (dst, etype) keys: deg[d*8+t]; 3-phase scan (n = N*8)
// ---------------------------------------------------------------------------
__global__ __launch_bounds__(256) void count_deg_kernel(
    const int* __restrict__ dst, const int* __restrict__ etype,
    int* __restrict__ deg, int E) {
  int e = blockIdx.x * 256 + threadIdx.x;
  if (e < E) atomicAdd(&deg[dst[e] * 8 + etype[e]], 1);
}

__global__ __launch_bounds__(256) void scan_p1(const int* __restrict__ deg,
                                               int* __restrict__ bsum, int n) {
  int base = blockIdx.x * SCHUNK + threadIdx.x * 8;
  int s = 0;
#pragma unroll
  for (int j = 0; j < 8; j++) {
    int i = base + j;
    if (i < n) s += deg[i];
  }
#pragma unroll
  for (int d = 1; d < 64; d <<= 1) s += __shfl_xor(s, d, 64);
  __shared__ int ws[4];
  if ((threadIdx.x & 63) == 0) ws[threadIdx.x >> 6] = s;
  __syncthreads();
  if (threadIdx.x == 0) bsum[blockIdx.x] = ws[0] + ws[1] + ws[2] + ws[3];
}

// 256-thread exclusive scan (nb up to 256)
__global__ __launch_bounds__(256) void scan_p2(int* bsum, int nb) {
  __shared__ int wsum[4];
  const int i = threadIdx.x;
  int v = (i < nb) ? bsum[i] : 0;
  const int orig = v;
  const int lane = i & 63, w = i >> 6;
#pragma unroll
  for (int d = 1; d < 64; d <<= 1) {
    int up = __shfl_up(v, d, 64);
    if (lane >= d) v += up;
  }
  if (lane == 63) wsum[w] = v;
  __syncthreads();
  int woff = 0;
#pragma unroll
  for (int k = 0; k < 4; k++) woff += (k < w) ? wsum[k] : 0;
  if (i < nb) bsum[i] = woff + v - orig;
}

__global__ __launch_bounds__(256) void scan_p3(const int* __restrict__ deg,
                                               const int* __restrict__ bsum,
                                               int* __restrict__ row_ptr,
                                               int n) {
  int base = blockIdx.x * SCHUNK + threadIdx.x * 8;
  int vals[8];
  int s = 0;
#pragma unroll
  for (int j = 0; j < 8; j++) {
    int i = base + j;
    vals[j] = (i < n) ? deg[i] : 0;
    s += vals[j];
  }
  int lane = threadIdx.x & 63, w = threadIdx.x >> 6;
  int v = s;
#pragma unroll
  for (int d = 1; d < 64; d <<= 1) {
    int up = __shfl_up(v, d, 64);
    if (lane >= d) v += up;
  }
  __shared__ int wsum[4];
  if (lane == 63) wsum[w] = v;
  __syncthreads();
  int woff = 0;
#pragma unroll
  for (int i = 0; i < 4; i++) woff += (i < w) ? wsum[i] : 0;
  int off = bsum[blockIdx.x] + woff + v - s;
#pragma unroll
  for (int j = 0; j < 8; j++) {
    int i = base + j;
    off += vals[j];
    if (i < n) row_ptr[i + 1] = off;
  }
  if (blockIdx.x == 0 && threadIdx.x == 0) row_ptr[0] = 0;
}

// ---------------------------------------------------------------------------
// Bucketed edge placement (2-pass). Edges end up sorted by (dst, etype):
// contiguous per-(dst,r) segments via rp2 CSR (N*8+1 entries).
// ---------------------------------------------------------------------------
__global__ __launch_bounds__(256) void bucket_cursor_init(
    const int* __restrict__ rp2, int* __restrict__ cursor, int N, int nb) {
  int i = threadIdx.x;
  if (i < nb) cursor[i] = rp2[(size_t)min(i * 256, N) * 8];
}

__global__ __launch_bounds__(256) void bucket_pass1(
    const int* __restrict__ src, const int* __restrict__ dst,
    const int* __restrict__ etype, int* __restrict__ cursor,
    unsigned* __restrict__ tmp, int E) {
  __shared__ int hist[256];
  __shared__ int binstart[256];
  __shared__ int gbase[256];
  __shared__ int fill[256];
  __shared__ int wsum[4];
  __shared__ unsigned stage[EPB];
  __shared__ unsigned char binof[EPB];
  const int tid = threadIdx.x;
  const int e0 = blockIdx.x * EPB;
  const int cnt = min(EPB, E - e0);

  hist[tid] = 0;
  fill[tid] = 0;
  __syncthreads();
  for (int j = tid; j < cnt; j += 256) atomicAdd(&hist[dst[e0 + j] >> 8], 1);
  __syncthreads();

  const int hv = hist[tid];
  {
    const int lane = tid & 63, w = tid >> 6;
    int iv = hv;
#pragma unroll
    for (int d = 1; d < 64; d <<= 1) {
      int up = __shfl_up(iv, d, 64);
      if (lane >= d) iv += up;
    }
    if (lane == 63) wsum[w] = iv;
    __syncthreads();
    int woff = 0;
#pragma unroll
    for (int i = 0; i < 4; i++) woff += (i < w) ? wsum[i] : 0;
    binstart[tid] = woff + iv - hv;  // exclusive prefix
    if (hv > 0) gbase[tid] = atomicAdd(&cursor[tid], hv);
  }
  __syncthreads();

  for (int j = tid; j < cnt; j += 256) {
    const int d = dst[e0 + j];
    const int b = d >> 8;
    const unsigned rec = ((unsigned)(d & 255) << 19) |
                         ((unsigned)etype[e0 + j] << 16) |
                         (unsigned)src[e0 + j];
    const int slot = binstart[b] + atomicAdd(&fill[b], 1);
    stage[slot] = rec;
    binof[slot] = (unsigned char)b;
  }
  __syncthreads();

  for (int s = tid; s < cnt; s += 256) {
    const int b = binof[s];
    tmp[gbase[b] + (s - binstart[b])] = stage[s];
  }
}

// pass 2: one block per bucket; 2048 LDS bins (256 rows x 8 relations).
__global__ __launch_bounds__(256) void bucket_pass2(
    const int* __restrict__ rp2, const unsigned* __restrict__ tmp,
    int* __restrict__ edges, int N) {
  __shared__ int rp[2049];
  __shared__ int fill[2048];
  const int tid = threadIdx.x;
  const int rowbase = blockIdx.x * 256;
  const int rowcnt = min(256, N - rowbase);
  for (int i = tid; i <= rowcnt * 8; i += 256)
    rp[i] = rp2[(size_t)rowbase * 8 + i];
  for (int i = tid; i < 2048; i += 256) fill[i] = 0;
  __syncthreads();
  const int beg = rp[0];
  const int endv = rp[rowcnt * 8];
  for (int i = beg + tid; i < endv; i += 256) {
    const unsigned rec = tmp[i];
    const int bin = rec >> 16;  // dlow8*8 | etype3 (11 bits)
    const int pos = rp[bin] + atomicAdd(&fill[bin], 1);
    edges[pos] = (int)(rec & 0x7FFFFu);  // src | etype<<16
  }
}

// ---------------------------------------------------------------------------
// Layer-1 transform via MFMA bf16 (grid (R, nb64)), STRIPPED epilogue:
// pure {MFMA -> bf16 pack -> coalesced t-store}.
// ---------------------------------------------------------------------------
__global__ __launch_bounds__(256) void transform1_mfma(
    const unsigned short* __restrict__ xb,
    const unsigned short* __restrict__ W1t, unsigned short* __restrict__ tb,
    int N) {
  __shared__ unsigned short st[4][16][72];
  const int r = blockIdx.x;
  const int tid = threadIdx.x;
  const int w = tid >> 6;
  const int lane = tid & 63;
  const int quad = lane >> 4;
  const int mrow = lane & 15;
  const int n0w = blockIdx.y * 64 + w * 16;

  const int gA = min(n0w + mrow, N - 1);
  const unsigned short* arow = xb + (size_t)gA * 128 + quad * 8;
  const unsigned short* wrow = W1t + ((size_t)r * 64 + mrow) * 128 + quad * 8;

  v4f acc[4];
#pragma unroll
  for (int tt = 0; tt < 4; tt++) acc[tt] = (v4f){0.f, 0.f, 0.f, 0.f};

#pragma unroll
  for (int k0 = 0; k0 < 128; k0 += 32) {
    v8s a = *(const v8s*)(arow + k0);
#pragma unroll
    for (int tt = 0; tt < 4; tt++) {
      v8s b = *(const v8s*)(wrow + (size_t)tt * 16 * 128 + k0);
      acc[tt] = __builtin_amdgcn_mfma_f32_16x16x32_bf16(a, b, acc[tt], 0, 0, 0);
    }
  }

#pragma unroll
  for (int i = 0; i < 4; i++)
#pragma unroll
    for (int tt = 0; tt < 4; tt++)
      st[w][quad * 4 + i][tt * 16 + mrow] =
          (unsigned short)f2bf_rne(acc[tt][i]);
  __syncthreads();

  const int row = lane >> 2, cg = lane & 3;
  const int gns = n0w + row;
  if (gns < N) {
    const uint4 v0 = *(const uint4*)&st[w][row][cg * 16];
    const uint4 v1 = *(const uint4*)&st[w][row][cg * 16 + 8];
    uint4* dst = (uint4*)&tb[((size_t)r * N + gns) * 64 + cg * 16];
    dst[0] = v0;
    dst[1] = v1;
  }
}

// ---------------------------------------------------------------------------
// Layer-1 logits from T1 directions: aq1[r,n] = x_n.T1[r],
// ak1[r,n] = x_n.T1[8+r]; folded rowmax (clone of validated logit2).
// ---------------------------------------------------------------------------
__global__ __launch_bounds__(256) void logit1_kernel(
    const unsigned short* __restrict__ xb, const float* __restrict__ T1,
    float* __restrict__ aq1, float* __restrict__ ak1,
    unsigned* __restrict__ maxk_enc, int N) {
  __shared__ float Ts[2048];  // 16 x 128
  __shared__ float wred[4][8];
  for (int i = threadIdx.x; i < 2048; i += 256) Ts[i] = T1[i];
  __syncthreads();
  const int n0 = blockIdx.x * 256 + threadIdx.x;
  const bool valid = n0 < N;
  const int n = valid ? n0 : N - 1;
  const unsigned short* xr = xb + (size_t)n * 128;

  float dq[8], dk[8];
#pragma unroll
  for (int j = 0; j < 8; j++) {
    dq[j] = 0.f;
    dk[j] = 0.f;
  }
  for (int d = 0; d < 16; d++) {  // 8 channels per chunk
    const uint4 u = *(const uint4*)(xr + d * 8);
    float xv[8];
    xv[0] = __uint_as_float(u.x << 16);
    xv[1] = __uint_as_float(u.x & 0xFFFF0000u);
    xv[2] = __uint_as_float(u.y << 16);
    xv[3] = __uint_as_float(u.y & 0xFFFF0000u);
    xv[4] = __uint_as_float(u.z << 16);
    xv[5] = __uint_as_float(u.z & 0xFFFF0000u);
    xv[6] = __uint_as_float(u.w << 16);
    xv[7] = __uint_as_float(u.w & 0xFFFF0000u);
    const int base = d * 8;
#pragma unroll
    for (int j = 0; j < 8; j++) {
#pragma unroll
      for (int c = 0; c < 8; c++) {
        dq[j] = fmaf(xv[c], Ts[j * 128 + base + c], dq[j]);
        dk[j] = fmaf(xv[c], Ts[(8 + j) * 128 + base + c], dk[j]);
      }
    }
  }

  const int lane = threadIdx.x & 63, w = threadIdx.x >> 6;
#pragma unroll
  for (int j = 0; j < 8; j++) {
    if (valid) {
      aq1[(size_t)j * N + n] = dq[j];
      ak1[(size_t)j * N + n] = dk[j];
    }
    float kmx = dk[j];  // invalid lanes dup node N-1: max unaffected
#pragma unroll
    for (int d = 1; d < 64; d <<= 1)
      kmx = fmaxf(kmx, __shfl_xor(kmx, d, 64));
    if (lane == 0) wred[w][j] = kmx;
  }
  __syncthreads();
  if (threadIdx.x < 8) {
    const float bm = fmaxf(fmaxf(wred[0][threadIdx.x], wred[1][threadIdx.x]),
                           fmaxf(wred[2][threadIdx.x], wred[3][threadIdx.x]));
    atomicMax(&maxk_enc[threadIdx.x], fenc(bm));
  }
}

// ---------------------------------------------------------------------------
// Layer-1 aggregate: R1-exact best-measured form (u-loop group gather),
// node edge range via rp2 (all 8 relation segments contiguous).
// ---------------------------------------------------------------------------
__global__ __launch_bounds__(256) void aggregate_kernel(
    const int* __restrict__ rp2, const int* __restrict__ edges,
    const unsigned short* __restrict__ tb, const float* __restrict__ aq,
    const float* __restrict__ ak, const unsigned* __restrict__ maxk_enc,
    const float* __restrict__ bias, unsigned short* __restrict__ hb, int N) {
  const int tid = threadIdx.x;
  const int w = tid >> 6, o = tid & 63;
  int wid = blockIdx.x * 4 + w;
  const bool valid = wid < N;
  if (!valid) wid = N - 1;
  const int beg = rp2[(size_t)wid * 8];
  const int end = valid ? rp2[(size_t)wid * 8 + 8] : beg;
  const int deg = end - beg;

  const float aqw = aq[(size_t)(o & 7) * N + wid];

  float v = aqw + fdec(maxk_enc[o & 7]);
  v = (v >= 0.f) ? v : NEG_SLOPE * v;
#pragma unroll
  for (int d = 1; d < 8; d <<= 1) v = fmaxf(v, __shfl_xor(v, d, 64));
  const float m = __shfl(v, 0, 64);

  const int g = o >> 3;  // edge-group 0..7 (8 edges per gather iter)
  const int cl = o & 7;  // channel lane: owns channels 8*cl .. 8*cl+7
  float s = 0.f;
  float acc[8];
#pragma unroll
  for (int c = 0; c < 8; c++) acc[c] = 0.f;

  for (int base = 0; base < deg; base += 64) {
    const int j = base + o;
    const int gcount = min(64, deg - base);
    const int packed = edges[beg + min(j, deg - 1)];
    const int src = packed & 0xFFFF;
    const int rr = packed >> 16;
    const int idx = rr * N + src;
    float x = __shfl(aqw, rr, 64) + ak[idx];
    x = (x >= 0.f) ? x : NEG_SLOPE * x;
    const float p = (j < deg) ? __expf(x - m) : 0.f;
    s += p;
    const int g8 = (gcount + 7) & ~7;
    for (int u = 0; u < g8; u += 8) {
      const int e = u + g;
      const float pe = __shfl(p, e, 64);   // 0 for padded slots
      const int ie = __shfl(idx, e, 64);   // clamped-valid index
      const uint4 tv = *(const uint4*)(tb + (size_t)ie * 64 + cl * 8);
      const unsigned uu0 = tv.x, uu1 = tv.y, uu2 = tv.z, uu3 = tv.w;
      acc[0] = fmaf(pe, __uint_as_float(uu0 << 16), acc[0]);
      acc[1] = fmaf(pe, __uint_as_float(uu0 & 0xFFFF0000u), acc[1]);
      acc[2] = fmaf(pe, __uint_as_float(uu1 << 16), acc[2]);
      acc[3] = fmaf(pe, __uint_as_float(uu1 & 0xFFFF0000u), acc[3]);
      acc[4] = fmaf(pe, __uint_as_float(uu2 << 16), acc[4]);
      acc[5] = fmaf(pe, __uint_as_float(uu2 & 0xFFFF0000u), acc[5]);
      acc[6] = fmaf(pe, __uint_as_float(uu3 << 16), acc[6]);
      acc[7] = fmaf(pe, __uint_as_float(uu3 & 0xFFFF0000u), acc[7]);
    }
  }
#pragma unroll
  for (int d = 1; d < 64; d <<= 1) s += __shfl_xor(s, d, 64);
#pragma unroll
  for (int d = 8; d < 64; d <<= 1) {
#pragma unroll
    for (int c = 0; c < 8; c++) acc[c] += __shfl_xor(acc[c], d, 64);
  }

  if (valid && g == 0) {
    const float inv = 1.f / (s + 1e-16f);
    unsigned rv[8];
#pragma unroll
    for (int c = 0; c < 8; c++) {
      const float res = acc[c] * inv + bias[cl * 8 + c];
      rv[c] = f2bf_rne(fmaxf(res, 0.f));
    }
    uint4 pkd;
    pkd.x = rv[0] | (rv[1] << 16);
    pkd.y = rv[2] | (rv[3] << 16);
    pkd.z = rv[4] | (rv[5] << 16);
    pkd.w = rv[6] | (rv[7] << 16);
    *(uint4*)(hb + (size_t)wid * 64 + cl * 8) = pkd;
  }
}

// ---------------------------------------------------------------------------
// Layer-2 logits: aq2[j,n] = h_n.T[j], ak2[j,n] = h_n.T[16+j]; folded rowmax.
// ---------------------------------------------------------------------------
__global__ __launch_bounds__(256) void logit2_kernel(
    const unsigned short* __restrict__ hb, const float* __restrict__ T,
    float* __restrict__ aq2, float* __restrict__ ak2,
    unsigned* __restrict__ maxk2_enc, int N) {
  __shared__ float Ts[2048];
  __shared__ float wred[4][16];
  for (int i = threadIdx.x; i < 2048; i += 256) Ts[i] = T[i];
  __syncthreads();
  const int n0 = blockIdx.x * 256 + threadIdx.x;
  const bool valid = n0 < N;
  const int n = valid ? n0 : N - 1;
  float h[64];
  const unsigned short* hr = hb + (size_t)n * 64;
#pragma unroll
  for (int d = 0; d < 8; d++) {
    const uint4 u = *(const uint4*)(hr + d * 8);
    h[d * 8 + 0] = __uint_as_float(u.x << 16);
    h[d * 8 + 1] = __uint_as_float(u.x & 0xFFFF0000u);
    h[d * 8 + 2] = __uint_as_float(u.y << 16);
    h[d * 8 + 3] = __uint_as_float(u.y & 0xFFFF0000u);
    h[d * 8 + 4] = __uint_as_float(u.z << 16);
    h[d * 8 + 5] = __uint_as_float(u.z & 0xFFFF0000u);
    h[d * 8 + 6] = __uint_as_float(u.w << 16);
    h[d * 8 + 7] = __uint_as_float(u.w & 0xFFFF0000u);
  }
  float kmx[16];
#pragma unroll
  for (int j = 0; j < 16; j++) {
    float dq = 0.f, dk = 0.f;
#pragma unroll
    for (int c = 0; c < 64; c++) {
      dq = fmaf(h[c], Ts[j * 64 + c], dq);
      dk = fmaf(h[c], Ts[(16 + j) * 64 + c], dk);
    }
    if (valid) {
      aq2[(size_t)j * N + n] = dq;
      ak2[(size_t)j * N + n] = dk;
    }
    kmx[j] = dk;  // invalid lanes carry node N-1 dup: max unaffected
  }
  const int lane = threadIdx.x & 63, w = threadIdx.x >> 6;
#pragma unroll
  for (int j = 0; j < 16; j++) {
#pragma unroll
    for (int d = 1; d < 64; d <<= 1)
      kmx[j] = fmaxf(kmx[j], __shfl_xor(kmx[j], d, 64));
    if (lane == 0) wred[w][j] = kmx[j];
  }
  __syncthreads();
  if (threadIdx.x < 16) {
    const float bm = fmaxf(fmaxf(wred[0][threadIdx.x], wred[1][threadIdx.x]),
                           fmaxf(wred[2][threadIdx.x], wred[3][threadIdx.x]));
    atomicMax(&maxk2_enc[threadIdx.x], fenc(bm));
  }
}

// ---------------------------------------------------------------------------
// Layer-2 aggregate, relation-factored, REGISTER-ONLY (R6-validated):
// one wave = one node; 8-lane group = one relation segment (static r);
// lane owns 8 channels of the 128B h row. No LDS, no atomics.
// ---------------------------------------------------------------------------
__global__ __launch_bounds__(256) void aggregate2g_kernel(
    const int* __restrict__ rp2, const int* __restrict__ edges,
    const unsigned short* __restrict__ hb, const float* __restrict__ aq2,
    const float* __restrict__ ak2, const unsigned* __restrict__ maxk2_enc,
    unsigned* __restrict__ y, float* __restrict__ sbuf, int N) {
  const int tid = threadIdx.x;
  const int w = tid >> 6, o = tid & 63;
  int wid = blockIdx.x * 4 + w;
  const bool valid = wid < N;
  if (!valid) wid = N - 1;

  // global upper-bound shift (same as validated R3/R6 path)
  const float aqw = aq2[(size_t)(o & 15) * N + wid];
  float v = aqw + fdec(maxk2_enc[o & 15]);
  v = (v >= 0.f) ? v : NEG_SLOPE * v;
#pragma unroll
  for (int d = 1; d < 8; d <<= 1) v = fmaxf(v, __shfl_xor(v, d, 64));
  const float m0 = __shfl(v, 0, 64);
  const float m1 = __shfl(v, 8, 64);

  const int grp = o >> 3;  // relation 0..7 (static per lane)
  const int ln = o & 7;    // channel octet: ch 8*ln .. 8*ln+7
  const float aqr0 = __shfl(aqw, grp, 64);
  const float aqr1 = __shfl(aqw, 8 + grp, 64);

  const int sb = rp2[(size_t)wid * 8 + grp];
  const int se = rp2[(size_t)wid * 8 + grp + 1];

  float acc0[8], acc1[8];
#pragma unroll
  for (int c = 0; c < 8; c++) {
    acc0[c] = 0.f;
    acc1[c] = 0.f;
  }
  float s0 = 0.f, s1 = 0.f;

  const size_t akoff0 = (size_t)grp * N;
  const size_t akoff1 = (size_t)(8 + grp) * N;
  for (int e = sb; e < se; ++e) {
    const int src = edges[e] & 0xFFFF;  // same addr across the 8-lane group
    const float akv0 = ak2[akoff0 + src];
    const float akv1 = ak2[akoff1 + src];
    const uint4 hv = *(const uint4*)(hb + (size_t)src * 64 + ln * 8);
    float x0 = aqr0 + akv0;
    float x1 = aqr1 + akv1;
    x0 = (x0 >= 0.f) ? x0 : NEG_SLOPE * x0;
    x1 = (x1 >= 0.f) ? x1 : NEG_SLOPE * x1;
    const float p0 = __expf(x0 - m0);
    const float p1 = __expf(x1 - m1);
    s0 += p0;
    s1 += p1;
    const unsigned uu0 = hv.x, uu1 = hv.y, uu2 = hv.z, uu3 = hv.w;
    const float h0 = __uint_as_float(uu0 << 16);
    const float h1 = __uint_as_float(uu0 & 0xFFFF0000u);
    const float h2 = __uint_as_float(uu1 << 16);
    const float h3 = __uint_as_float(uu1 & 0xFFFF0000u);
    const float h4 = __uint_as_float(uu2 << 16);
    const float h5 = __uint_as_float(uu2 & 0xFFFF0000u);
    const float h6 = __uint_as_float(uu3 << 16);
    const float h7 = __uint_as_float(uu3 & 0xFFFF0000u);
    acc0[0] = fmaf(p0, h0, acc0[0]);
    acc0[1] = fmaf(p0, h1, acc0[1]);
    acc0[2] = fmaf(p0, h2, acc0[2]);
    acc0[3] = fmaf(p0, h3, acc0[3]);
    acc0[4] = fmaf(p0, h4, acc0[4]);
    acc0[5] = fmaf(p0, h5, acc0[5]);
    acc0[6] = fmaf(p0, h6, acc0[6]);
    acc0[7] = fmaf(p0, h7, acc0[7]);
    acc1[0] = fmaf(p1, h0, acc1[0]);
    acc1[1] = fmaf(p1, h1, acc1[1]);
    acc1[2] = fmaf(p1, h2, acc1[2]);
    acc1[3] = fmaf(p1, h3, acc1[3]);
    acc1[4] = fmaf(p1, h4, acc1[4]);
    acc1[5] = fmaf(p1, h5, acc1[5]);
    acc1[6] = fmaf(p1, h6, acc1[6]);
    acc1[7] = fmaf(p1, h7, acc1[7]);
  }

  if (valid) {
    // element k = r*64 + ch; word j holds (2j, 2j+1); our words = 4*o .. +3
    uint4 p0w, p1w;
    p0w.x = f2bf_rne(acc0[0]) | (f2bf_rne(acc0[1]) << 16);
    p0w.y = f2bf_rne(acc0[2]) | (f2bf_rne(acc0[3]) << 16);
    p0w.z = f2bf_rne(acc0[4]) | (f2bf_rne(acc0[5]) << 16);
    p0w.w = f2bf_rne(acc0[6]) | (f2bf_rne(acc0[7]) << 16);
    p1w.x = f2bf_rne(acc1[0]) | (f2bf_rne(acc1[1]) << 16);
    p1w.y = f2bf_rne(acc1[2]) | (f2bf_rne(acc1[3]) << 16);
    p1w.z = f2bf_rne(acc1[4]) | (f2bf_rne(acc1[5]) << 16);
    p1w.w = f2bf_rne(acc1[6]) | (f2bf_rne(acc1[7]) << 16);
    *(uint4*)(y + (size_t)wid * 256 + 4 * o) = p0w;
    *(uint4*)(y + ((size_t)N + wid) * 256 + 4 * o) = p1w;
  }

  // total softmax sums: group values identical within group; xor over
  // distances 8/16/32 sums each of the 8 groups exactly once.
#pragma unroll
  for (int d = 8; d < 64; d <<= 1) {
    s0 += __shfl_xor(s0, d, 64);
    s1 += __shfl_xor(s1, d, 64);
  }
  if (valid && o == 0) {
    sbuf[(size_t)wid * 2 + 0] = s0;
    sbuf[(size_t)wid * 2 + 1] = s1;
  }
}

// ---------------------------------------------------------------------------
// Layer-2 epilogue, DOUBLE-MFMA form:
//   stage 1: hidden = relu((y @ Wcat)/s + b_conv)    (MFMA K=512, as before)
//   stage 2: out    = hidden @ Wlin + b              (MFMA K=64 via LDS bf16)
// Replaces the per-thread 64-MAC LDS matvec (~1024 ds_read_b32/thread) that
// was the measured bottleneck (78us, 200K bank conflicts, MfmaUtil 3%).
// ---------------------------------------------------------------------------
__global__ __launch_bounds__(256) void out2_kernel(
    const unsigned short* __restrict__ yb,
    const unsigned short* __restrict__ Wct, const float* __restrict__ sbuf,
    const float* __restrict__ bmu, const float* __restrict__ blv,
    const unsigned short* __restrict__ Wlt2, const float* __restrict__ bm,
    const float* __restrict__ bl, float* __restrict__ out_mu,
    float* __restrict__ out_ls, int N) {
  __shared__ unsigned short hst[64][80];  // bf16 hidden; 160B row stride
  const int s = blockIdx.y;
  const int tid = threadIdx.x;
  const int w = tid >> 6, lane = tid & 63;
  const int quad = lane >> 4, mrow = lane & 15;
  const int n0w = blockIdx.x * 64 + w * 16;
  const int gA = min(n0w + mrow, N - 1);
  const unsigned short* arow = yb + ((size_t)s * N + gA) * 512 + quad * 8;
  const unsigned short* wrow = Wct + ((size_t)s * 64 + mrow) * 512 + quad * 8;

  v4f acc[4];
#pragma unroll
  for (int tt = 0; tt < 4; tt++) acc[tt] = (v4f){0.f, 0.f, 0.f, 0.f};
#pragma unroll
  for (int k0 = 0; k0 < 512; k0 += 32) {
    v8s a = *(const v8s*)(arow + k0);
#pragma unroll
    for (int tt = 0; tt < 4; tt++) {
      v8s b = *(const v8s*)(wrow + (size_t)tt * 16 * 512 + k0);
      acc[tt] = __builtin_amdgcn_mfma_f32_16x16x32_bf16(a, b, acc[tt], 0, 0, 0);
    }
  }

  // hidden -> bf16 LDS (each wave writes & reads only its own 16 rows)
  const float* bc = s ? blv : bmu;
#pragma unroll
  for (int i = 0; i < 4; i++) {
    const int node = min(n0w + quad * 4 + i, N - 1);
    const float inv = 1.f / (sbuf[(size_t)node * 2 + s] + 1e-16f);
#pragma unroll
    for (int tt = 0; tt < 4; tt++) {
      hst[w * 16 + quad * 4 + i][tt * 16 + mrow] = (unsigned short)f2bf_rne(
          fmaxf(acc[tt][i] * inv + bc[tt * 16 + mrow], 0.f));
    }
  }
  __syncthreads();

  // stage 2: hidden[16x64] @ Wlin^T[32x64] per wave (4 MFMA)
  const unsigned short* ar2 = &hst[w * 16 + mrow][quad * 8];
  v4f acc2[2];
  acc2[0] = (v4f){0.f, 0.f, 0.f, 0.f};
  acc2[1] = (v4f){0.f, 0.f, 0.f, 0.f};
#pragma unroll
  for (int st2 = 0; st2 < 2; st2++) {
    v8s a2 = *(const v8s*)(ar2 + st2 * 32);
#pragma unroll
    for (int t2 = 0; t2 < 2; t2++) {
      v8s b2v = *(const v8s*)(Wlt2 + ((size_t)s * 32 + t2 * 16 + mrow) * 64 +
                              quad * 8 + st2 * 32);
      acc2[t2] =
          __builtin_amdgcn_mfma_f32_16x16x32_bf16(a2, b2v, acc2[t2], 0, 0, 0);
    }
  }

  const float* b2 = s ? bl : bm;
  const float mul = s ? 0.5f : 1.f;
  float* outp = s ? out_ls : out_mu;
#pragma unroll
  for (int t2 = 0; t2 < 2; t2++) {
    const float bo = b2[t2 * 16 + mrow];
#pragma unroll
    for (int i = 0; i < 4; i++) {
      const int node = n0w + quad * 4 + i;
      if (node < N)
        outp[(size_t)node * 32 + t2 * 16 + mrow] = (acc2[t2][i] + bo) * mul;
    }
  }
}

// ---------------------------------------------------------------------------
extern "C" void kernel_launch(void* const* d_in, const int* in_sizes, int n_in,
                              void* d_out, int out_size, void* d_ws,
                              size_t ws_size, hipStream_t stream) {
  const float* x = (const float*)d_in[0];
  const int* edge_index = (const int*)d_in[1];
  const int* edge_type = (const int*)d_in[2];
  const float* W1 = (const float*)d_in[3];
  const float* q1 = (const float*)d_in[4];
  const float* k1 = (const float*)d_in[5];
  const float* b1 = (const float*)d_in[6];
  const float* Wmu = (const float*)d_in[7];
  const float* qmu = (const float*)d_in[8];
  const float* kmu = (const float*)d_in[9];
  const float* bmu = (const float*)d_in[10];
  const float* Wlv = (const float*)d_in[11];
  const float* qlv = (const float*)d_in[12];
  const float* klv = (const float*)d_in[13];
  const float* blv = (const float*)d_in[14];
  const float* Wm = (const float*)d_in[15];
  const float* bm = (const float*)d_in[16];
  const float* Wl = (const float*)d_in[17];
  const float* bl = (const float*)d_in[18];

  const int N = in_sizes[0] / 128;         // 50000
  const int E = in_sizes[2];               // 1.6M
  const int R = in_sizes[3] / (128 * 64);  // 8

  float* out_mu = (float*)d_out;
  float* out_ls = (float*)d_out + (size_t)N * ODIM;

  char* wsp = (char*)d_ws;
  size_t off = 0;
  auto carve = [&](size_t bytes) {
    void* p = wsp + off;
    off += (bytes + 255) & ~(size_t)255;
    return p;
  };

  // tbuf: layer-1 bf16 t (51.2 MB), then reused as y [2][N][512] bf16 (102.4)
  void* tbuf = carve((size_t)R * N * 64 * sizeof(unsigned));
  unsigned short* t1b = (unsigned short*)tbuf;
  unsigned short* yb = (unsigned short*)tbuf;
  unsigned* yw = (unsigned*)tbuf;
  unsigned short* xb = (unsigned short*)carve((size_t)N * 128 * 2);
  unsigned short* hb = (unsigned short*)carve((size_t)N * 64 * 2);
  unsigned short* W1t = (unsigned short*)carve((size_t)R * 64 * 128 * 2);
  unsigned short* Wct = (unsigned short*)carve((size_t)2 * 64 * 512 * 2);
  unsigned short* Wlt2 = (unsigned short*)carve((size_t)2 * 32 * 64 * 2);
  float* Tdir = (float*)carve((size_t)4096 * sizeof(float));
  float* aq2 = (float*)carve((size_t)2 * R * N * sizeof(float));
  float* ak2 = (float*)carve((size_t)2 * R * N * sizeof(float));
  unsigned* maxk_enc = (unsigned*)carve(32 * sizeof(unsigned));
  float* sbuf = (float*)carve((size_t)N * 2 * sizeof(float));
  int* deg = (int*)carve((size_t)N * 8 * sizeof(int));
  int* rp2 = (int*)carve(((size_t)N * 8 + 1) * sizeof(int));
  int* bsum = (int*)carve(256 * sizeof(int));
  int* cursor = (int*)carve(256 * sizeof(int));
  unsigned* tmp = (unsigned*)carve((size_t)E * sizeof(unsigned));
  int* edges = (int*)carve((size_t)E * sizeof(int));

  const int* e_src = edge_index;
  const int* e_dst = edge_index + E;

  // ---- prep: bf16 conversions + weight transposes + logit tables ----
  cvt_bf16_kernel<<<(N * 128 / 4 + 255) / 256, 256, 0, stream>>>(x, xb,
                                                                 N * 128);
  transpose_w_kernel<<<26, 256, 0, stream>>>(W1, Wmu, Wlv, Wm, Wl, W1t, Wct,
                                             Wlt2);
  prep_T_kernel<<<2, 256, 0, stream>>>(W1, q1, k1, Wmu, qmu, kmu, Wlv, qlv,
                                       klv, Tdir);

  // ---- CSR over (dst, etype) ----
  hipMemsetAsync(deg, 0, (size_t)N * 8 * sizeof(int), stream);
  hipMemsetAsync(maxk_enc, 0, 32 * sizeof(unsigned), stream);
  count_deg_kernel<<<(E + 255) / 256, 256, 0, stream>>>(e_dst, edge_type, deg,
                                                        E);
  const int n2 = N * 8;
  const int nchunk = (n2 + SCHUNK - 1) / SCHUNK;
  scan_p1<<<nchunk, 256, 0, stream>>>(deg, bsum, n2);
  scan_p2<<<1, 256, 0, stream>>>(bsum, nchunk);
  scan_p3<<<nchunk, 256, 0, stream>>>(deg, bsum, rp2, n2);

  // ---- bucketed edge placement -> edges sorted by (dst, r) ----
  const int nbuck = (N + 255) >> 8;  // 196 <= 256
  bucket_cursor_init<<<1, 256, 0, stream>>>(rp2, cursor, N, nbuck);
  bucket_pass1<<<(E + EPB - 1) / EPB, 256, 0, stream>>>(e_src, e_dst,
                                                        edge_type, cursor,
                                                        tmp, E);
  bucket_pass2<<<nbuck, 256, 0, stream>>>(rp2, tmp, edges, N);

  const int nb64 = (N + 63) / 64;
  const int agg_blocks = (N + 3) / 4;

  // ---- layer 1: IN=128 -> H=64 (stripped MFMA transform + T1 logits) ----
  transform1_mfma<<<dim3(R, nb64), 256, 0, stream>>>(xb, W1t, t1b, N);
  logit1_kernel<<<(N + 255) / 256, 256, 0, stream>>>(xb, Tdir + 2048, aq2,
                                                     ak2, maxk_enc, N);
  aggregate_kernel<<<agg_blocks, 256, 0, stream>>>(rp2, edges, t1b, aq2, ak2,
                                                   maxk_enc, b1, hb, N);

  // ---- layer 2: relation-factored, register-only aggregation over h ----
  logit2_kernel<<<(N + 255) / 256, 256, 0, stream>>>(hb, Tdir, aq2, ak2,
                                                     maxk_enc + 8, N);
  aggregate2g_kernel<<<agg_blocks, 256, 0, stream>>>(
      rp2, edges, hb, aq2, ak2, maxk_enc + 8, yw, sbuf, N);
  out2_kernel<<<dim3(nb64, 2), 256, 0, stream>>>(yb, Wct, sbuf, bmu, blv,
                                                 Wlt2, bm, bl, out_mu, out_ls,
                                                 N);
}